// Round 9
// baseline (863.009 us; speedup 1.0000x reference)
//
#include <hip/hip_runtime.h>
#include <cstdio>
#include <cstdint>

#define N_NODES 100000
#define N_EDGES 600000
#define DIM     128
#define NSETS   3
#define NLAYERS 2
#define NGRAPH  64
#define NPASS   2
#define GT      3125      // gather tiles (32 nodes each)
#define MT      1563      // node tiles (64 nodes each)  -- also k_pool grid
#define PB      85        // persistent gemm blocks per set (3*PB = 255 <= 256 CUs, 1 block/CU)

typedef __bf16 bf16x8 __attribute__((ext_vector_type(8)));
typedef float  f32x4  __attribute__((ext_vector_type(4)));
typedef unsigned short u16;

static __device__ __forceinline__ float bf2f(u16 u) {
    return __uint_as_float(((uint32_t)u) << 16);
}
// native RNE f32->bf16 (compiler emits v_cvt_pk_bf16_f32; same rounding as manual RNE)
static __device__ __forceinline__ u16 f2bf(float f) {
    union { __bf16 b; u16 u; } c;
    c.b = (__bf16)f;
    return c.u;
}
static __device__ __forceinline__ uint32_t packbf(float lo, float hi) {
    return (uint32_t)f2bf(lo) | ((uint32_t)f2bf(hi) << 16);
}
static __device__ __forceinline__ void unpack_add(uint32_t u, float& a0, float& a1) {
    a0 += __uint_as_float(u << 16);
    a1 += __uint_as_float(u & 0xFFFF0000u);
}
static __device__ __forceinline__ float fast_rcp(float x) {
    return __builtin_amdgcn_rcpf(x);
}
static __device__ __forceinline__ float sigmoidf_(float x) {
    return fast_rcp(1.0f + __expf(-x));
}
static __device__ __forceinline__ float tanhf_(float x) {
    return 1.0f - 2.0f * fast_rcp(__expf(2.0f * x) + 1.0f);
}

// async global->LDS, 16 B per lane; LDS dest = wave-uniform base + lane*16
static __device__ __forceinline__ void gload_lds16(const u16* g, u16* l) {
    __builtin_amdgcn_global_load_lds(
        (const __attribute__((address_space(1))) void*)g,
        (__attribute__((address_space(3))) void*)l, 16, 0, 0);
}

// ---------------- dtype detection ----------------
__global__ void k_detect(const u16* __restrict__ x, int* __restrict__ flag) {
    __shared__ float red[256];
    float m = 0.0f;
    for (int i = threadIdx.x; i < 8192; i += 256) {
        float f = __uint_as_float(((uint32_t)x[i]) << 16);
        f = fabsf(f);
        if (isnan(f)) f = 3.0e38f;
        m = fmaxf(m, f);
    }
    red[threadIdx.x] = m;
    __syncthreads();
    for (int off = 128; off > 0; off >>= 1) {
        if (threadIdx.x < off) red[threadIdx.x] = fmaxf(red[threadIdx.x], red[threadIdx.x + off]);
        __syncthreads();
    }
    if (threadIdx.x == 0) flag[0] = (red[0] < 1.0e6f) ? 1 : 0;
}

// ---------------- converts ----------------
__global__ void k_to_bf(const void* __restrict__ src, u16* __restrict__ dst,
                        int n, const int* __restrict__ flag) {
    const int f = *flag;
    for (int i = blockIdx.x * blockDim.x + threadIdx.x; i < n; i += gridDim.x * blockDim.x) {
        if (f) dst[i] = ((const u16*)src)[i];
        else   dst[i] = f2bf(((const float*)src)[i]);
    }
}

// all 9 small fp32 conversions in ONE launch (biases + MLP weights + problemType)
// ranges: bih 1152 | bhh 1152 | fc1w 10320 | fc1b 80 | fc2w 6400 | fc2b 80
//         fclw 160 | fclb 2 | ptf 64  -> total 19410
__global__ void k_convsmall(const void* __restrict__ b0, const void* __restrict__ b1,
                            const void* __restrict__ w1, const void* __restrict__ c1,
                            const void* __restrict__ w2, const void* __restrict__ c2,
                            const void* __restrict__ wl, const void* __restrict__ cl,
                            const void* __restrict__ pt,
                            float* __restrict__ d_b0, float* __restrict__ d_b1,
                            float* __restrict__ d_w1, float* __restrict__ d_c1,
                            float* __restrict__ d_w2, float* __restrict__ d_c2,
                            float* __restrict__ d_wl, float* __restrict__ d_cl,
                            float* __restrict__ d_pt,
                            const int* __restrict__ flag) {
    const int f = *flag;
    const int i = blockIdx.x * 256 + threadIdx.x;
    const void* src; float* dst; int off;
    if      (i < 1152)  { src = b0; dst = d_b0; off = i; }
    else if (i < 2304)  { src = b1; dst = d_b1; off = i - 1152; }
    else if (i < 12624) { src = w1; dst = d_w1; off = i - 2304; }
    else if (i < 12704) { src = c1; dst = d_c1; off = i - 12624; }
    else if (i < 19104) { src = w2; dst = d_w2; off = i - 12704; }
    else if (i < 19184) { src = c2; dst = d_c2; off = i - 19104; }
    else if (i < 19344) { src = wl; dst = d_wl; off = i - 19184; }
    else if (i < 19346) { src = cl; dst = d_cl; off = i - 19344; }
    else if (i < 19410) { src = pt; dst = d_pt; off = i - 19346; }
    else return;
    float v;
    if (f) v = bf2f(((const u16*)src)[off]);
    else   v = ((const float*)src)[off];
    dst[off] = v;
}

// Wf[sl][n][j] = sum_d wih[s][n][d] * Wraw[sl][j][d]   (reads W raw, contiguous in d;
// bit-identical to the old transpose+fuse: same values, same summation order)
__global__ void k_fuse(const void* __restrict__ W_raw, const void* __restrict__ wih_raw,
                       u16* __restrict__ hi, u16* __restrict__ lo,
                       const int* __restrict__ flag) {
    const int f = *flag;
    const int i = blockIdx.x * 256 + threadIdx.x;
    const int sl = i / 49152;
    const int rem = i - sl * 49152;
    const int n = rem >> 7;
    const int j = rem & 127;
    const int s = sl >> 1;
    const int wtb = (sl << 14) + j * 128;   // Wraw[sl][j][*]
    const int wb = (s * 384 + n) * 128;
    float acc = 0.0f;
#pragma unroll 8
    for (int d = 0; d < 128; ++d) {
        float wv, wt;
        if (f) { wv = bf2f(((const u16*)wih_raw)[wb + d]); wt = bf2f(((const u16*)W_raw)[wtb + d]); }
        else   { wv = ((const float*)wih_raw)[wb + d];     wt = ((const float*)W_raw)[wtb + d]; }
        acc = fmaf(wv, wt, acc);
    }
    u16 h = f2bf(acc);
    hi[i] = h;
    lo[i] = f2bf(acc - bf2f(h));
}

// whh: [S][384][128] -> hi/lo bf16
__global__ void k_prep_G(const void* __restrict__ src, u16* __restrict__ hi,
                         u16* __restrict__ lo, const int* __restrict__ flag) {
    const int total = NSETS * 384 * DIM;
    const int f = *flag;
    for (int i = blockIdx.x * blockDim.x + threadIdx.x; i < total; i += gridDim.x * blockDim.x) {
        float v;
        if (f) v = bf2f(((const u16*)src)[i]);
        else   v = ((const float*)src)[i];
        u16 h = f2bf(v);
        hi[i] = h;
        lo[i] = f2bf(v - bf2f(h));
    }
}

// ---------------- CSR build ----------------
__global__ void k_deg(const int* __restrict__ ei, const int* __restrict__ attr,
                      int* __restrict__ cnt) {
    int e = blockIdx.x * 256 + threadIdx.x;
    if (e < N_EDGES) {
        int t = attr[e];
        int d = ei[N_EDGES + e];
        atomicAdd(&cnt[t * N_NODES + d], 1);
    }
}

__global__ void k_scan1(const int* __restrict__ cnt, int* __restrict__ rp,
                        int* __restrict__ part, int n) {
    __shared__ int buf[1024];
    int gid = blockIdx.x * 1024 + threadIdx.x;
    int v = (gid < n) ? cnt[gid] : 0;
    buf[threadIdx.x] = v;
    __syncthreads();
    for (int off = 1; off < 1024; off <<= 1) {
        int t = (threadIdx.x >= off) ? buf[threadIdx.x - off] : 0;
        __syncthreads();
        buf[threadIdx.x] += t;
        __syncthreads();
    }
    if (gid < n) rp[gid] = buf[threadIdx.x] - v;
    if (threadIdx.x == 1023) part[blockIdx.x] = buf[1023];
}

__global__ void k_scan2(int* __restrict__ part, int nb) {
    __shared__ int buf[1024];
    int v = (threadIdx.x < nb) ? part[threadIdx.x] : 0;
    buf[threadIdx.x] = v;
    __syncthreads();
    for (int off = 1; off < 1024; off <<= 1) {
        int t = (threadIdx.x >= off) ? buf[threadIdx.x - off] : 0;
        __syncthreads();
        buf[threadIdx.x] += t;
        __syncthreads();
    }
    if (threadIdx.x < nb) part[threadIdx.x] = buf[threadIdx.x] - v;
}

__global__ void k_scan3(int* __restrict__ rp, int* __restrict__ cursor,
                        const int* __restrict__ part, int n) {
    int gid = blockIdx.x * 1024 + threadIdx.x;
    if (gid < n) {
        int v = rp[gid] + part[blockIdx.x];
        rp[gid] = v;
        cursor[gid] = v;
    }
    if (gid == 0) rp[n] = N_EDGES;
}

__global__ void k_fill(const int* __restrict__ ei, const int* __restrict__ attr,
                       int* __restrict__ cursor, int* __restrict__ col) {
    int e = blockIdx.x * 256 + threadIdx.x;
    if (e < N_EDGES) {
        int t = attr[e];
        int d = ei[N_EDGES + e];
        int s = ei[e];
        int pos = atomicAdd(&cursor[t * N_NODES + d], 1);
        col[pos] = s;
    }
}

// ---------------- gather (standalone: 6 blocks/CU hides the 3-deep load chain) ----------------
__global__ void __launch_bounds__(256, 6)
k_gather(const u16* __restrict__ s0, const u16* __restrict__ s1, const u16* __restrict__ s2,
         u16* __restrict__ d0, u16* __restrict__ d1, u16* __restrict__ d2,
         const int* __restrict__ rp, const int* __restrict__ colarr) {
    const int bx = blockIdx.x;
    const int set = bx / GT;
    const int tile = bx - set * GT;
    const u16* __restrict__ src = (set == 0) ? s0 : (set == 1) ? s1 : s2;
    u16* __restrict__ dst = (set == 0) ? d0 : (set == 1) ? d1 : d2;
    const int* __restrict__ rp_s = rp + set * N_NODES;

    const int nl = threadIdx.x >> 3;
    const int q  = threadIdx.x & 7;
    const int gn = tile * 32 + nl;

    float a[16];
#pragma unroll
    for (int j = 0; j < 16; ++j) a[j] = 0.0f;

    const int beg = rp_s[gn], end = rp_s[gn + 1];
    int dg = end - beg; if (dg < 1) dg = 1;
    const float inv = 1.0f / (float)dg;

    int e = beg;
    for (; e + 2 <= end; e += 2) {
        const int c0 = colarr[e];
        const int c1 = colarr[e + 1];
        const uint4* m0 = (const uint4*)(src + (size_t)c0 * DIM + q * 16);
        const uint4* m1 = (const uint4*)(src + (size_t)c1 * DIM + q * 16);
        uint4 v0 = m0[0], v1 = m0[1], w0 = m1[0], w1 = m1[1];
        unpack_add(v0.x, a[0], a[1]);   unpack_add(v0.y, a[2], a[3]);
        unpack_add(v0.z, a[4], a[5]);   unpack_add(v0.w, a[6], a[7]);
        unpack_add(v1.x, a[8], a[9]);   unpack_add(v1.y, a[10], a[11]);
        unpack_add(v1.z, a[12], a[13]); unpack_add(v1.w, a[14], a[15]);
        unpack_add(w0.x, a[0], a[1]);   unpack_add(w0.y, a[2], a[3]);
        unpack_add(w0.z, a[4], a[5]);   unpack_add(w0.w, a[6], a[7]);
        unpack_add(w1.x, a[8], a[9]);   unpack_add(w1.y, a[10], a[11]);
        unpack_add(w1.z, a[12], a[13]); unpack_add(w1.w, a[14], a[15]);
    }
    if (e < end) {
        const int c0 = colarr[e];
        const uint4* m0 = (const uint4*)(src + (size_t)c0 * DIM + q * 16);
        uint4 v0 = m0[0], v1 = m0[1];
        unpack_add(v0.x, a[0], a[1]);   unpack_add(v0.y, a[2], a[3]);
        unpack_add(v0.z, a[4], a[5]);   unpack_add(v0.w, a[6], a[7]);
        unpack_add(v1.x, a[8], a[9]);   unpack_add(v1.y, a[10], a[11]);
        unpack_add(v1.z, a[12], a[13]); unpack_add(v1.w, a[14], a[15]);
    }
#pragma unroll
    for (int j = 0; j < 16; ++j) a[j] *= inv;

    uint4* d = (uint4*)(dst + (size_t)gn * DIM + q * 16);
    d[0] = make_uint4(packbf(a[0], a[1]), packbf(a[2], a[3]),
                      packbf(a[4], a[5]), packbf(a[6], a[7]));
    d[1] = make_uint4(packbf(a[8], a[9]), packbf(a[10], a[11]),
                      packbf(a[12], a[13]), packbf(a[14], a[15]));
}

// ---------------- persistent fused GEMM+GRU: weights VGPR-resident ----------------
// Round-7 measured-known-good version (107us/dispatch). Each wave preloads its
// full weight set ONCE (32 bf16x8 = 128 VGPR), eliminating the per-iteration
// L2 weight re-stream. 1 block/CU (grid 3*85=255), ~18 tiles/block, merged
// A/H K-loop, A triple-buffered / H double-buffered LDS (80KB), stage via
// global_load_lds, stores issued after bar#2 and drained at the next
// iteration's loop-top barrier. (r8's counted-vmcnt variant regressed: the
// sched_barrier fences pinned the schedule — reverted.)
__global__ void __launch_bounds__(512, 2)
k_gemm(const u16* __restrict__ g0, const u16* __restrict__ g1, const u16* __restrict__ g2,
       const u16* __restrict__ o0, const u16* __restrict__ o1, const u16* __restrict__ o2,
       u16* __restrict__ d0, u16* __restrict__ d1, u16* __restrict__ d2,
       const u16* __restrict__ Wf_hi, const u16* __restrict__ Wf_lo,
       const u16* __restrict__ whh_hi, const u16* __restrict__ whh_lo,
       const float* __restrict__ bih, const float* __restrict__ bhh, int layer)
{
    __shared__ u16 sA0[16 * 512], sA1[16 * 512], sA2[16 * 512];   // agg: triple buffer
    __shared__ u16 sH0[16 * 512], sH1[16 * 512];                  // own h: double buffer

    const int tid  = threadIdx.x;
    const int lane = tid & 63;
    const int wv   = tid >> 6;        // 0..7
    const int l15  = lane & 15;
    const int quad = lane >> 4;
    const int col  = wv * 16 + l15;   // this lane's output column

    const int set  = blockIdx.x / PB;
    const int part = blockIdx.x - set * PB;

    const u16* __restrict__ gsrc = (set == 0) ? g0 : (set == 1) ? g1 : g2;
    const u16* __restrict__ osrc = (set == 0) ? o0 : (set == 1) ? o1 : o2;
    u16* __restrict__ dst        = (set == 0) ? d0 : (set == 1) ? d1 : d2;
    const u16* wf_hi = Wf_hi + (size_t)(set * NLAYERS + layer) * 384 * DIM;
    const u16* wf_lo = Wf_lo + (size_t)(set * NLAYERS + layer) * 384 * DIM;
    const u16* wh_hi = whh_hi + (size_t)set * 384 * DIM;
    const u16* wh_lo = whh_lo + (size_t)set * 384 * DIM;
    const float* bi_s = bih + (size_t)set * 384;
    const float* bh_s = bhh + (size_t)set * 384;

    // store coords: 64 rows x 8 chunk-pairs of 32 B
    const int srow = tid >> 3;
    const int sq   = tid & 7;

    // biases for this lane's column
    const float b_r = bi_s[col] + bh_s[col];
    const float b_z = bi_s[128 + col] + bh_s[128 + col];
    const float bin = bi_s[256 + col];
    const float bhn = bh_s[256 + col];

    // weight row offsets (u16 elements)
    const int pr = col * 128 + quad * 8;
    const int pz = (128 + col) * 128 + quad * 8;
    const int pn = (256 + col) * 128 + quad * 8;

    // ---- preload ALL weights into registers (32 x bf16x8 = 128 VGPR) ----
    bf16x8 fr[4], fz[4], fh[4], fl[4], hr[4], hz[4], hh[4], hl[4];
#pragma unroll
    for (int ks = 0; ks < 4; ++ks) {
        const int k0 = ks * 32;
        fr[ks] = *(const bf16x8*)(wf_hi + pr + k0);
        fz[ks] = *(const bf16x8*)(wf_hi + pz + k0);
        fh[ks] = *(const bf16x8*)(wf_hi + pn + k0);
        fl[ks] = *(const bf16x8*)(wf_lo + pn + k0);
        hr[ks] = *(const bf16x8*)(wh_hi + pr + k0);
        hz[ks] = *(const bf16x8*)(wh_hi + pz + k0);
        hh[ks] = *(const bf16x8*)(wh_hi + pn + k0);
        hl[ks] = *(const bf16x8*)(wh_lo + pn + k0);
    }

    // chunk-major u16 index base for this lane's column (epilogue/hv)
    const int cbase = ((col >> 3) << 9) + (col & 7);   // chunk*512 + within-chunk

    // stage one 64-row tile of A and H into chunk-major LDS (4 gload_lds16/wave)
    auto stage = [&](u16* sa, u16* sh, int tile) {
        int nn = tile * 64 + lane;
        if (nn >= N_NODES) nn = N_NODES - 1;           // tail rows: garbage, never stored
        const u16* ga = gsrc + (size_t)nn * DIM;
        const u16* gh = osrc + (size_t)nn * DIM;
        const int c0 = wv * 2;                         // wave handles chunks c0, c0+1
        gload_lds16(ga + c0 * 8,     sa + c0 * 512);
        gload_lds16(ga + c0 * 8 + 8, sa + c0 * 512 + 512);
        gload_lds16(gh + c0 * 8,     sh + c0 * 512);
        gload_lds16(gh + c0 * 8 + 8, sh + c0 * 512 + 512);
    };

    u16 *aCur = sA0, *aNext = sA1, *aNext2 = sA2;
    u16 *hCur = sH0, *hNext = sH1;

    stage(aCur, hCur, part);   // prologue (latency exposed once, overlaps weight preload)
    __syncthreads();

    for (int tile = part; tile < MT; tile += PB) {
        // ---- issue next-tile prefetch FIRST (hidden under this tile's compute) ----
        if (tile + PB < MT) stage(aNext, hNext, tile + PB);

        const u16* sAc = aCur;
        const u16* sHc = hCur;

        f32x4 accR[4], accZ[4], accI[4], accH[4];
#pragma unroll
        for (int mt = 0; mt < 4; ++mt) {
            accR[mt] = (f32x4){0.f, 0.f, 0.f, 0.f};
            accZ[mt] = (f32x4){0.f, 0.f, 0.f, 0.f};
            accI[mt] = (f32x4){0.f, 0.f, 0.f, 0.f};
            accH[mt] = (f32x4){0.f, 0.f, 0.f, 0.f};
        }

        // ---- single merged K-loop: zero global loads inside (weights in VGPRs) ----
#pragma unroll
        for (int ks = 0; ks < 4; ++ks) {
            const int cb = (ks * 4 + quad) << 9;       // chunk base (u16 idx)
#pragma unroll
            for (int mt = 0; mt < 4; ++mt) {
                bf16x8 ag = *(const bf16x8*)&sAc[cb + (mt * 16 + l15) * 8];
                accR[mt] = __builtin_amdgcn_mfma_f32_16x16x32_bf16(ag, fr[ks], accR[mt], 0, 0, 0);
                accZ[mt] = __builtin_amdgcn_mfma_f32_16x16x32_bf16(ag, fz[ks], accZ[mt], 0, 0, 0);
                accI[mt] = __builtin_amdgcn_mfma_f32_16x16x32_bf16(ag, fh[ks], accI[mt], 0, 0, 0);
                accI[mt] = __builtin_amdgcn_mfma_f32_16x16x32_bf16(ag, fl[ks], accI[mt], 0, 0, 0);
                bf16x8 ah = *(const bf16x8*)&sHc[cb + (mt * 16 + l15) * 8];
                accR[mt] = __builtin_amdgcn_mfma_f32_16x16x32_bf16(ah, hr[ks], accR[mt], 0, 0, 0);
                accZ[mt] = __builtin_amdgcn_mfma_f32_16x16x32_bf16(ah, hz[ks], accZ[mt], 0, 0, 0);
                accH[mt] = __builtin_amdgcn_mfma_f32_16x16x32_bf16(ah, hh[ks], accH[mt], 0, 0, 0);
                accH[mt] = __builtin_amdgcn_mfma_f32_16x16x32_bf16(ah, hl[ks], accH[mt], 0, 0, 0);
            }
        }

        // ---- barrier #1: all frag reads done; outstanding vmem (stage, prev
        //      stores) had a full compute phase of head start -> cheap drain ----
        __syncthreads();

        // ---- epilogue: combine -> bf16 into aCur (dead region) ----
#pragma unroll
        for (int mt = 0; mt < 4; ++mt)
#pragma unroll
            for (int r = 0; r < 4; ++r) {
                const int row = mt * 16 + quad * 4 + r;
                const float rr = sigmoidf_(accR[mt][r] + b_r);
                const float zz = sigmoidf_(accZ[mt][r] + b_z);
                const float nn = tanhf_((accI[mt][r] + bin) + rr * (accH[mt][r] + bhn));
                const float hv = bf2f(sHc[cbase + row * 8]);
                aCur[cbase + row * 8] = f2bf((1.0f - zz) * nn + zz * hv);
            }

        // ---- barrier #2: only LDS writes since #1 -> lgkm-only drain, cheap ----
        __syncthreads();

        // ---- async store: drains at a later barrier ----
        const int sgn = tile * 64 + srow;
        if (sgn < N_NODES) {
            uint4 v0 = *(const uint4*)&aCur[(2 * sq) * 512 + srow * 8];
            uint4 v1 = *(const uint4*)&aCur[(2 * sq + 1) * 512 + srow * 8];
            uint4* d = (uint4*)(dst + (size_t)sgn * DIM + sq * 16);
            d[0] = v0; d[1] = v1;
        }

        // rotate buffers: A 3-cycle, H 2-cycle
        u16* ta = aCur; aCur = aNext; aNext = aNext2; aNext2 = ta;
        u16* th = hCur; hCur = hNext; hNext = th;
    }
}

// ---------------- x = (a+b+c)/3 (bf16) ----------------
__global__ void k_avg3(const u16* __restrict__ a, const u16* __restrict__ b,
                       const u16* __restrict__ c, u16* __restrict__ d) {
    const int i = blockIdx.x * 256 + threadIdx.x;
    const uint4 va = ((const uint4*)a)[i];
    const uint4 vb = ((const uint4*)b)[i];
    const uint4 vc = ((const uint4*)c)[i];
    const float third = 1.0f / 3.0f;
    auto comb = [&](uint32_t x, uint32_t y, uint32_t z) -> uint32_t {
        float l = 0.f, h = 0.f;
        unpack_add(x, l, h); unpack_add(y, l, h); unpack_add(z, l, h);
        return packbf(l * third, h * third);
    };
    uint4 vo;
    vo.x = comb(va.x, vb.x, vc.x);
    vo.y = comb(va.y, vb.y, vc.y);
    vo.z = comb(va.z, vb.z, vc.z);
    vo.w = comb(va.w, vb.w, vc.w);
    ((uint4*)d)[i] = vo;
}

// ---------------- pooling (bf16 x) ----------------
__global__ void k_pool(const u16* __restrict__ xf, const int* __restrict__ batch,
                       float* __restrict__ pooled, int* __restrict__ gcnt) {
    const int tid = threadIdx.x;
    const int f = tid & 127;
    const int half = tid >> 7;
    const int nstart = blockIdx.x * 64 + half * 32;
    float accv = 0.0f;
    int curg = -1, cnt = 0;
    for (int t = 0; t < 32; ++t) {
        const int n = nstart + t;
        if (n >= N_NODES) break;
        const int g = batch[n];
        if (g != curg) {
            if (curg >= 0) {
                atomicAdd(&pooled[curg * DIM + f], accv);
                if (f == 0) atomicAdd(&gcnt[curg], cnt);
            }
            curg = g; accv = 0.0f; cnt = 0;
        }
        accv += bf2f(xf[(size_t)n * DIM + f]);
        cnt++;
    }
    if (curg >= 0) {
        atomicAdd(&pooled[curg * DIM + f], accv);
        if (f == 0) atomicAdd(&gcnt[curg], cnt);
    }
}

// ---------------- MLP head: one block per graph ----------------
__global__ void k_head(const float* __restrict__ pooled, const int* __restrict__ gcnt,
                       const float* __restrict__ ptf,
                       const float* __restrict__ fc1w, const float* __restrict__ fc1b,
                       const float* __restrict__ fc2w, const float* __restrict__ fc2b,
                       const float* __restrict__ fclw, const float* __restrict__ fclb,
                       void* __restrict__ out, const int* __restrict__ flag) {
    __shared__ float xh[129];
    __shared__ float h1[80];
    __shared__ float h2[80];
    const int g   = blockIdx.x;
    const int tid = threadIdx.x;

    if (tid < 128) {
        int c = gcnt[g]; if (c < 1) c = 1;
        xh[tid] = pooled[g * 128 + tid] / (float)c;
    }
    if (tid == 0) xh[128] = ptf[g];
    __syncthreads();

    if (tid < 80) {
        float s = fc1b[tid];
        const float* wr = &fc1w[tid * 129];
#pragma unroll 16
        for (int k = 0; k < 129; ++k) s += xh[k] * wr[k];
        h1[tid] = (s > 0.0f) ? s : 0.01f * s;
    }
    __syncthreads();

    if (tid < 80) {
        float s = fc2b[tid];
        const float* wr = &fc2w[tid * 80];
#pragma unroll 16
        for (int k = 0; k < 80; ++k) s += h1[k] * wr[k];
        h2[tid] = (s > 0.0f) ? s : 0.01f * s;
    }
    __syncthreads();

    if (tid < 2) {
        float s = fclb[tid];
        const float* wr = &fclw[tid * 80];
#pragma unroll 16
        for (int k = 0; k < 80; ++k) s += h2[k] * wr[k];
        if (*flag) ((u16*)out)[g * 2 + tid] = f2bf(s);
        else       ((float*)out)[g * 2 + tid] = s;
    }
}

// ---------------- launcher ----------------
extern "C" void kernel_launch(void* const* d_in, const int* in_sizes, int n_in,
                              void* d_out, int out_size, void* d_ws, size_t ws_size,
                              hipStream_t stream) {
    if (n_in < 16) return;
    const void* x_in    = d_in[0];
    const int*  ei      = (const int*)d_in[1];
    const int*  attr    = (const int*)d_in[2];
    const int*  batch   = (const int*)d_in[3];
    const void* pt_in   = d_in[4];
    const void* W_in    = d_in[5];
    const void* wih_in  = d_in[6];
    const void* whh_in  = d_in[7];
    const void* bih_in  = d_in[8];
    const void* bhh_in  = d_in[9];
    const void* fc1w_in = d_in[10];
    const void* fc1b_in = d_in[11];
    const void* fc2w_in = d_in[12];
    const void* fc2b_in = d_in[13];
    const void* fclw_in = d_in[14];
    const void* fclb_in = d_in[15];

    char* ws = (char*)d_ws;
    size_t o = 0;
    auto alloc = [&](size_t b) { size_t r = o; o += (b + 255) & ~(size_t)255; return r; };

    const size_t NB2 = (size_t)N_NODES * DIM * 2;
    const size_t o_flag   = alloc(4);
    const size_t o_xbf    = alloc(NB2);
    const size_t o_A0     = alloc(NB2);
    const size_t o_A1     = alloc(NB2);
    const size_t o_A2     = alloc(NB2);
    const size_t o_B0     = alloc(NB2);
    const size_t o_B1     = alloc(NB2);
    const size_t o_Wf_hi  = alloc((size_t)NSETS * NLAYERS * 384 * DIM * 2);
    const size_t o_Wf_lo  = alloc((size_t)NSETS * NLAYERS * 384 * DIM * 2);
    const size_t o_whh_hi = alloc((size_t)NSETS * 384 * DIM * 2);
    const size_t o_whh_lo = alloc((size_t)NSETS * 384 * DIM * 2);
    const size_t o_bih    = alloc((size_t)NSETS * 384 * 4);
    const size_t o_bhh    = alloc((size_t)NSETS * 384 * 4);
    const size_t o_fc1w   = alloc(10320 * 4);
    const size_t o_fc1b   = alloc(80 * 4);
    const size_t o_fc2w   = alloc(6400 * 4);
    const size_t o_fc2b   = alloc(80 * 4);
    const size_t o_fclw   = alloc(160 * 4);
    const size_t o_fclb   = alloc(2 * 4);
    const size_t o_ptf    = alloc(64 * 4);
    const size_t o_cnt    = alloc(((size_t)3 * N_NODES + 1) * 4);
    const size_t o_cursor = alloc((size_t)3 * N_NODES * 4);
    const size_t o_col    = alloc((size_t)N_EDGES * 4);
    const int    nb_scan  = (3 * N_NODES + 1023) / 1024;
    const size_t o_part   = alloc((size_t)nb_scan * 4);
    const size_t o_pooled = alloc((size_t)NGRAPH * DIM * 4);
    const size_t o_gcnt   = alloc((size_t)NGRAPH * 4);

    if (ws_size < o) {
        fprintf(stderr, "GGNN kernel: workspace too small: need %zu, have %zu\n", o, ws_size);
        return;
    }

    int*   flag   = (int*)(ws + o_flag);
    u16*   xbf    = (u16*)(ws + o_xbf);
    u16*   A0     = (u16*)(ws + o_A0);
    u16*   A1     = (u16*)(ws + o_A1);
    u16*   A2     = (u16*)(ws + o_A2);
    u16*   B0     = (u16*)(ws + o_B0);
    u16*   B1     = (u16*)(ws + o_B1);
    u16*   Wf_hi  = (u16*)(ws + o_Wf_hi);
    u16*   Wf_lo  = (u16*)(ws + o_Wf_lo);
    u16*   whh_hi = (u16*)(ws + o_whh_hi);
    u16*   whh_lo = (u16*)(ws + o_whh_lo);
    float* bihf   = (float*)(ws + o_bih);
    float* bhhf   = (float*)(ws + o_bhh);
    float* fc1wf  = (float*)(ws + o_fc1w);
    float* fc1bf  = (float*)(ws + o_fc1b);
    float* fc2wf  = (float*)(ws + o_fc2w);
    float* fc2bf  = (float*)(ws + o_fc2b);
    float* fclwf  = (float*)(ws + o_fclw);
    float* fclbf  = (float*)(ws + o_fclb);
    float* ptf    = (float*)(ws + o_ptf);
    int*   cnt    = (int*)(ws + o_cnt);
    int*   rp     = cnt;
    int*   cursor = (int*)(ws + o_cursor);
    int*   col    = (int*)(ws + o_col);
    int*   part   = (int*)(ws + o_part);
    float* pooled = (float*)(ws + o_pooled);
    int*   gcnt   = (int*)(ws + o_gcnt);

    hipMemsetAsync(cnt, 0, (size_t)3 * N_NODES * 4, stream);
    hipMemsetAsync(pooled, 0, (o_gcnt - o_pooled) + (size_t)NGRAPH * 4, stream);

    k_detect<<<1, 256, 0, stream>>>((const u16*)x_in, flag);

    // converts + weight prep (k_transW eliminated; 9 small converts merged)
    k_to_bf<<<(N_NODES * DIM + 2047) / 2048, 256, 0, stream>>>(x_in, xbf, N_NODES * DIM, flag);
    k_fuse<<<(NSETS * NLAYERS * 384 * DIM) / 256, 256, 0, stream>>>(W_in, wih_in, Wf_hi, Wf_lo, flag);
    k_prep_G<<<(NSETS * 384 * DIM + 255) / 256, 256, 0, stream>>>(whh_in, whh_hi, whh_lo, flag);
    k_convsmall<<<(19410 + 255) / 256, 256, 0, stream>>>(
        bih_in, bhh_in, fc1w_in, fc1b_in, fc2w_in, fc2b_in, fclw_in, fclb_in, pt_in,
        bihf, bhhf, fc1wf, fc1bf, fc2wf, fc2bf, fclwf, fclbf, ptf, flag);

    // CSR build
    k_deg<<<(N_EDGES + 255) / 256, 256, 0, stream>>>(ei, attr, cnt);
    k_scan1<<<nb_scan, 1024, 0, stream>>>(cnt, rp, part, 3 * N_NODES);
    k_scan2<<<1, 1024, 0, stream>>>(part, nb_scan);
    k_scan3<<<nb_scan, 1024, 0, stream>>>(rp, cursor, part, 3 * N_NODES);
    k_fill<<<(N_EDGES + 255) / 256, 256, 0, stream>>>(ei, attr, cursor, col);

    // GGC passes (split gather + persistent weight-resident gemm)
    for (int pass = 0; pass < NPASS; ++pass) {
        k_gather<<<3 * GT, 256, 0, stream>>>(xbf, xbf, xbf, A0, A1, A2, rp, col);
        k_gemm<<<3 * PB, 512, 0, stream>>>(A0, A1, A2, xbf, xbf, xbf, A0, A1, A2,
                                           Wf_hi, Wf_lo, whh_hi, whh_lo, bihf, bhhf, 0);
        k_gather<<<3 * GT, 256, 0, stream>>>(A0, A1, A2, B0, B1, xbf, rp, col);
        k_gemm<<<3 * PB, 512, 0, stream>>>(B0, B1, xbf, A0, A1, A2, A0, A1, A2,
                                           Wf_hi, Wf_lo, whh_hi, whh_lo, bihf, bhhf, 1);
        k_avg3<<<(N_NODES * DIM / 8) / 256, 256, 0, stream>>>(A0, A1, A2, xbf);
    }

    // pooling + head (one block per graph)
    k_pool<<<MT, 256, 0, stream>>>(xbf, batch, pooled, gcnt);
    k_head<<<NGRAPH, 128, 0, stream>>>(pooled, gcnt, ptf, fc1wf, fc1bf, fc2wf, fc2bf,
                                       fclwf, fclbf, d_out, flag);
}

// Round 10
// 801.455 us; speedup vs baseline: 1.0768x; 1.0768x over previous
//
#include <hip/hip_runtime.h>
#include <cstdio>
#include <cstdint>

#define N_NODES 100000
#define N_EDGES 600000
#define DIM     128
#define NSETS   3
#define NLAYERS 2
#define NGRAPH  64
#define NPASS   2
#define GT      3125      // gather tiles (32 nodes each)
#define MT      1563      // node tiles (64 nodes each)  -- also k_pool grid
#define PB      85        // persistent gemm blocks per set (3*PB = 255 <= 256 CUs, 1 block/CU)

typedef __bf16 bf16x8 __attribute__((ext_vector_type(8)));
typedef float  f32x4  __attribute__((ext_vector_type(4)));
typedef unsigned short u16;

static __device__ __forceinline__ float bf2f(u16 u) {
    return __uint_as_float(((uint32_t)u) << 16);
}
// native RNE f32->bf16 (compiler emits v_cvt_pk_bf16_f32; same rounding as manual RNE)
static __device__ __forceinline__ u16 f2bf(float f) {
    union { __bf16 b; u16 u; } c;
    c.b = (__bf16)f;
    return c.u;
}
static __device__ __forceinline__ uint32_t packbf(float lo, float hi) {
    return (uint32_t)f2bf(lo) | ((uint32_t)f2bf(hi) << 16);
}
static __device__ __forceinline__ void unpack_add(uint32_t u, float& a0, float& a1) {
    a0 += __uint_as_float(u << 16);
    a1 += __uint_as_float(u & 0xFFFF0000u);
}
static __device__ __forceinline__ float fast_rcp(float x) {
    return __builtin_amdgcn_rcpf(x);
}
static __device__ __forceinline__ float sigmoidf_(float x) {
    return fast_rcp(1.0f + __expf(-x));
}
static __device__ __forceinline__ float tanhf_(float x) {
    return 1.0f - 2.0f * fast_rcp(__expf(2.0f * x) + 1.0f);
}

// async global->LDS, 16 B per lane; LDS dest = wave-uniform base + lane*16
static __device__ __forceinline__ void gload_lds16(const u16* g, u16* l) {
    __builtin_amdgcn_global_load_lds(
        (const __attribute__((address_space(1))) void*)g,
        (__attribute__((address_space(3))) void*)l, 16, 0, 0);
}

// ---------------- dtype detection ----------------
__global__ void k_detect(const u16* __restrict__ x, int* __restrict__ flag) {
    __shared__ float red[256];
    float m = 0.0f;
    for (int i = threadIdx.x; i < 8192; i += 256) {
        float f = __uint_as_float(((uint32_t)x[i]) << 16);
        f = fabsf(f);
        if (isnan(f)) f = 3.0e38f;
        m = fmaxf(m, f);
    }
    red[threadIdx.x] = m;
    __syncthreads();
    for (int off = 128; off > 0; off >>= 1) {
        if (threadIdx.x < off) red[threadIdx.x] = fmaxf(red[threadIdx.x], red[threadIdx.x + off]);
        __syncthreads();
    }
    if (threadIdx.x == 0) flag[0] = (red[0] < 1.0e6f) ? 1 : 0;
}

// ---------------- converts ----------------
__global__ void k_to_bf(const void* __restrict__ src, u16* __restrict__ dst,
                        int n, const int* __restrict__ flag) {
    const int f = *flag;
    for (int i = blockIdx.x * blockDim.x + threadIdx.x; i < n; i += gridDim.x * blockDim.x) {
        if (f) dst[i] = ((const u16*)src)[i];
        else   dst[i] = f2bf(((const float*)src)[i]);
    }
}

// all 9 small fp32 conversions in ONE launch (biases + MLP weights + problemType)
// ranges: bih 1152 | bhh 1152 | fc1w 10320 | fc1b 80 | fc2w 6400 | fc2b 80
//         fclw 160 | fclb 2 | ptf 64  -> total 19410
__global__ void k_convsmall(const void* __restrict__ b0, const void* __restrict__ b1,
                            const void* __restrict__ w1, const void* __restrict__ c1,
                            const void* __restrict__ w2, const void* __restrict__ c2,
                            const void* __restrict__ wl, const void* __restrict__ cl,
                            const void* __restrict__ pt,
                            float* __restrict__ d_b0, float* __restrict__ d_b1,
                            float* __restrict__ d_w1, float* __restrict__ d_c1,
                            float* __restrict__ d_w2, float* __restrict__ d_c2,
                            float* __restrict__ d_wl, float* __restrict__ d_cl,
                            float* __restrict__ d_pt,
                            const int* __restrict__ flag) {
    const int f = *flag;
    const int i = blockIdx.x * 256 + threadIdx.x;
    const void* src; float* dst; int off;
    if      (i < 1152)  { src = b0; dst = d_b0; off = i; }
    else if (i < 2304)  { src = b1; dst = d_b1; off = i - 1152; }
    else if (i < 12624) { src = w1; dst = d_w1; off = i - 2304; }
    else if (i < 12704) { src = c1; dst = d_c1; off = i - 12624; }
    else if (i < 19104) { src = w2; dst = d_w2; off = i - 12704; }
    else if (i < 19184) { src = c2; dst = d_c2; off = i - 19104; }
    else if (i < 19344) { src = wl; dst = d_wl; off = i - 19184; }
    else if (i < 19346) { src = cl; dst = d_cl; off = i - 19344; }
    else if (i < 19410) { src = pt; dst = d_pt; off = i - 19346; }
    else return;
    float v;
    if (f) v = bf2f(((const u16*)src)[off]);
    else   v = ((const float*)src)[off];
    dst[off] = v;
}

// W raw [S][L][j][d] -> Wt fp32 [sl][d][j]  (transpose exists so k_fuse's weight
// reads are COALESCED: lane index j lands in the fast dimension. Removing it in
// r9 made k_fuse 64-way scattered and cost ~50us — restored.)
__global__ void k_transW(const void* __restrict__ src, float* __restrict__ dst,
                         const int* __restrict__ flag) {
    const int total = NSETS * NLAYERS * DIM * DIM;
    const int f = *flag;
    for (int i = blockIdx.x * blockDim.x + threadIdx.x; i < total; i += gridDim.x * blockDim.x) {
        const int sl = i >> 14;
        const int rem = i & 16383;
        const int d = rem >> 7;
        const int j = rem & 127;
        const int si = (sl << 14) + j * 128 + d;
        float v;
        if (f) v = bf2f(((const u16*)src)[si]);
        else   v = ((const float*)src)[si];
        dst[i] = v;
    }
}

// Wf[sl][n][j] = sum_d wih[s][n][d] * Wt[sl][d][j]
__global__ void k_fuse(const float* __restrict__ Wt, const void* __restrict__ wih_raw,
                       u16* __restrict__ hi, u16* __restrict__ lo,
                       const int* __restrict__ flag) {
    const int f = *flag;
    const int i = blockIdx.x * 256 + threadIdx.x;
    const int sl = i / 49152;
    const int rem = i - sl * 49152;
    const int n = rem >> 7;
    const int j = rem & 127;
    const int s = sl >> 1;
    const float* wt = Wt + (sl << 14) + j;
    const int wb = (s * 384 + n) * 128;
    float acc = 0.0f;
#pragma unroll 8
    for (int d = 0; d < 128; ++d) {
        float wv;
        if (f) wv = bf2f(((const u16*)wih_raw)[wb + d]);
        else   wv = ((const float*)wih_raw)[wb + d];
        acc = fmaf(wv, wt[d * 128], acc);
    }
    u16 h = f2bf(acc);
    hi[i] = h;
    lo[i] = f2bf(acc - bf2f(h));
}

// whh: [S][384][128] -> hi/lo bf16
__global__ void k_prep_G(const void* __restrict__ src, u16* __restrict__ hi,
                         u16* __restrict__ lo, const int* __restrict__ flag) {
    const int total = NSETS * 384 * DIM;
    const int f = *flag;
    for (int i = blockIdx.x * blockDim.x + threadIdx.x; i < total; i += gridDim.x * blockDim.x) {
        float v;
        if (f) v = bf2f(((const u16*)src)[i]);
        else   v = ((const float*)src)[i];
        u16 h = f2bf(v);
        hi[i] = h;
        lo[i] = f2bf(v - bf2f(h));
    }
}

// ---------------- CSR build ----------------
__global__ void k_deg(const int* __restrict__ ei, const int* __restrict__ attr,
                      int* __restrict__ cnt) {
    int e = blockIdx.x * 256 + threadIdx.x;
    if (e < N_EDGES) {
        int t = attr[e];
        int d = ei[N_EDGES + e];
        atomicAdd(&cnt[t * N_NODES + d], 1);
    }
}

__global__ void k_scan1(const int* __restrict__ cnt, int* __restrict__ rp,
                        int* __restrict__ part, int n) {
    __shared__ int buf[1024];
    int gid = blockIdx.x * 1024 + threadIdx.x;
    int v = (gid < n) ? cnt[gid] : 0;
    buf[threadIdx.x] = v;
    __syncthreads();
    for (int off = 1; off < 1024; off <<= 1) {
        int t = (threadIdx.x >= off) ? buf[threadIdx.x - off] : 0;
        __syncthreads();
        buf[threadIdx.x] += t;
        __syncthreads();
    }
    if (gid < n) rp[gid] = buf[threadIdx.x] - v;
    if (threadIdx.x == 1023) part[blockIdx.x] = buf[1023];
}

__global__ void k_scan2(int* __restrict__ part, int nb) {
    __shared__ int buf[1024];
    int v = (threadIdx.x < nb) ? part[threadIdx.x] : 0;
    buf[threadIdx.x] = v;
    __syncthreads();
    for (int off = 1; off < 1024; off <<= 1) {
        int t = (threadIdx.x >= off) ? buf[threadIdx.x - off] : 0;
        __syncthreads();
        buf[threadIdx.x] += t;
        __syncthreads();
    }
    if (threadIdx.x < nb) part[threadIdx.x] = buf[threadIdx.x] - v;
}

__global__ void k_scan3(int* __restrict__ rp, int* __restrict__ cursor,
                        const int* __restrict__ part, int n) {
    int gid = blockIdx.x * 1024 + threadIdx.x;
    if (gid < n) {
        int v = rp[gid] + part[blockIdx.x];
        rp[gid] = v;
        cursor[gid] = v;
    }
    if (gid == 0) rp[n] = N_EDGES;
}

__global__ void k_fill(const int* __restrict__ ei, const int* __restrict__ attr,
                       int* __restrict__ cursor, int* __restrict__ col) {
    int e = blockIdx.x * 256 + threadIdx.x;
    if (e < N_EDGES) {
        int t = attr[e];
        int d = ei[N_EDGES + e];
        int s = ei[e];
        int pos = atomicAdd(&cursor[t * N_NODES + d], 1);
        col[pos] = s;
    }
}

// ---------------- gather (standalone: 6 blocks/CU hides the 3-deep load chain) ----------------
__global__ void __launch_bounds__(256, 6)
k_gather(const u16* __restrict__ s0, const u16* __restrict__ s1, const u16* __restrict__ s2,
         u16* __restrict__ d0, u16* __restrict__ d1, u16* __restrict__ d2,
         const int* __restrict__ rp, const int* __restrict__ colarr) {
    const int bx = blockIdx.x;
    const int set = bx / GT;
    const int tile = bx - set * GT;
    const u16* __restrict__ src = (set == 0) ? s0 : (set == 1) ? s1 : s2;
    u16* __restrict__ dst = (set == 0) ? d0 : (set == 1) ? d1 : d2;
    const int* __restrict__ rp_s = rp + set * N_NODES;

    const int nl = threadIdx.x >> 3;
    const int q  = threadIdx.x & 7;
    const int gn = tile * 32 + nl;

    float a[16];
#pragma unroll
    for (int j = 0; j < 16; ++j) a[j] = 0.0f;

    const int beg = rp_s[gn], end = rp_s[gn + 1];
    int dg = end - beg; if (dg < 1) dg = 1;
    const float inv = 1.0f / (float)dg;

    int e = beg;
    for (; e + 2 <= end; e += 2) {
        const int c0 = colarr[e];
        const int c1 = colarr[e + 1];
        const uint4* m0 = (const uint4*)(src + (size_t)c0 * DIM + q * 16);
        const uint4* m1 = (const uint4*)(src + (size_t)c1 * DIM + q * 16);
        uint4 v0 = m0[0], v1 = m0[1], w0 = m1[0], w1 = m1[1];
        unpack_add(v0.x, a[0], a[1]);   unpack_add(v0.y, a[2], a[3]);
        unpack_add(v0.z, a[4], a[5]);   unpack_add(v0.w, a[6], a[7]);
        unpack_add(v1.x, a[8], a[9]);   unpack_add(v1.y, a[10], a[11]);
        unpack_add(v1.z, a[12], a[13]); unpack_add(v1.w, a[14], a[15]);
        unpack_add(w0.x, a[0], a[1]);   unpack_add(w0.y, a[2], a[3]);
        unpack_add(w0.z, a[4], a[5]);   unpack_add(w0.w, a[6], a[7]);
        unpack_add(w1.x, a[8], a[9]);   unpack_add(w1.y, a[10], a[11]);
        unpack_add(w1.z, a[12], a[13]); unpack_add(w1.w, a[14], a[15]);
    }
    if (e < end) {
        const int c0 = colarr[e];
        const uint4* m0 = (const uint4*)(src + (size_t)c0 * DIM + q * 16);
        uint4 v0 = m0[0], v1 = m0[1];
        unpack_add(v0.x, a[0], a[1]);   unpack_add(v0.y, a[2], a[3]);
        unpack_add(v0.z, a[4], a[5]);   unpack_add(v0.w, a[6], a[7]);
        unpack_add(v1.x, a[8], a[9]);   unpack_add(v1.y, a[10], a[11]);
        unpack_add(v1.z, a[12], a[13]); unpack_add(v1.w, a[14], a[15]);
    }
#pragma unroll
    for (int j = 0; j < 16; ++j) a[j] *= inv;

    uint4* d = (uint4*)(dst + (size_t)gn * DIM + q * 16);
    d[0] = make_uint4(packbf(a[0], a[1]), packbf(a[2], a[3]),
                      packbf(a[4], a[5]), packbf(a[6], a[7]));
    d[1] = make_uint4(packbf(a[8], a[9]), packbf(a[10], a[11]),
                      packbf(a[12], a[13]), packbf(a[14], a[15]));
}

// ---------------- persistent fused GEMM+GRU: weights VGPR-resident ----------------
// Round-7 measured-known-good version (~104-107us/dispatch). Each wave preloads
// its full weight set ONCE (32 bf16x8 = 128 VGPR), eliminating the
// per-iteration L2 weight re-stream. 1 block/CU (grid 3*85=255), ~18
// tiles/block, merged A/H K-loop, A triple-buffered / H double-buffered LDS
// (80KB), stage via global_load_lds, stores issued after bar#2 and drained at
// the next iteration's loop-top barrier.
__global__ void __launch_bounds__(512, 2)
k_gemm(const u16* __restrict__ g0, const u16* __restrict__ g1, const u16* __restrict__ g2,
       const u16* __restrict__ o0, const u16* __restrict__ o1, const u16* __restrict__ o2,
       u16* __restrict__ d0, u16* __restrict__ d1, u16* __restrict__ d2,
       const u16* __restrict__ Wf_hi, const u16* __restrict__ Wf_lo,
       const u16* __restrict__ whh_hi, const u16* __restrict__ whh_lo,
       const float* __restrict__ bih, const float* __restrict__ bhh, int layer)
{
    __shared__ u16 sA0[16 * 512], sA1[16 * 512], sA2[16 * 512];   // agg: triple buffer
    __shared__ u16 sH0[16 * 512], sH1[16 * 512];                  // own h: double buffer

    const int tid  = threadIdx.x;
    const int lane = tid & 63;
    const int wv   = tid >> 6;        // 0..7
    const int l15  = lane & 15;
    const int quad = lane >> 4;
    const int col  = wv * 16 + l15;   // this lane's output column

    const int set  = blockIdx.x / PB;
    const int part = blockIdx.x - set * PB;

    const u16* __restrict__ gsrc = (set == 0) ? g0 : (set == 1) ? g1 : g2;
    const u16* __restrict__ osrc = (set == 0) ? o0 : (set == 1) ? o1 : o2;
    u16* __restrict__ dst        = (set == 0) ? d0 : (set == 1) ? d1 : d2;
    const u16* wf_hi = Wf_hi + (size_t)(set * NLAYERS + layer) * 384 * DIM;
    const u16* wf_lo = Wf_lo + (size_t)(set * NLAYERS + layer) * 384 * DIM;
    const u16* wh_hi = whh_hi + (size_t)set * 384 * DIM;
    const u16* wh_lo = whh_lo + (size_t)set * 384 * DIM;
    const float* bi_s = bih + (size_t)set * 384;
    const float* bh_s = bhh + (size_t)set * 384;

    // store coords: 64 rows x 8 chunk-pairs of 32 B
    const int srow = tid >> 3;
    const int sq   = tid & 7;

    // biases for this lane's column
    const float b_r = bi_s[col] + bh_s[col];
    const float b_z = bi_s[128 + col] + bh_s[128 + col];
    const float bin = bi_s[256 + col];
    const float bhn = bh_s[256 + col];

    // weight row offsets (u16 elements)
    const int pr = col * 128 + quad * 8;
    const int pz = (128 + col) * 128 + quad * 8;
    const int pn = (256 + col) * 128 + quad * 8;

    // ---- preload ALL weights into registers (32 x bf16x8 = 128 VGPR) ----
    bf16x8 fr[4], fz[4], fh[4], fl[4], hr[4], hz[4], hh[4], hl[4];
#pragma unroll
    for (int ks = 0; ks < 4; ++ks) {
        const int k0 = ks * 32;
        fr[ks] = *(const bf16x8*)(wf_hi + pr + k0);
        fz[ks] = *(const bf16x8*)(wf_hi + pz + k0);
        fh[ks] = *(const bf16x8*)(wf_hi + pn + k0);
        fl[ks] = *(const bf16x8*)(wf_lo + pn + k0);
        hr[ks] = *(const bf16x8*)(wh_hi + pr + k0);
        hz[ks] = *(const bf16x8*)(wh_hi + pz + k0);
        hh[ks] = *(const bf16x8*)(wh_hi + pn + k0);
        hl[ks] = *(const bf16x8*)(wh_lo + pn + k0);
    }

    // chunk-major u16 index base for this lane's column (epilogue/hv)
    const int cbase = ((col >> 3) << 9) + (col & 7);   // chunk*512 + within-chunk

    // stage one 64-row tile of A and H into chunk-major LDS (4 gload_lds16/wave)
    auto stage = [&](u16* sa, u16* sh, int tile) {
        int nn = tile * 64 + lane;
        if (nn >= N_NODES) nn = N_NODES - 1;           // tail rows: garbage, never stored
        const u16* ga = gsrc + (size_t)nn * DIM;
        const u16* gh = osrc + (size_t)nn * DIM;
        const int c0 = wv * 2;                         // wave handles chunks c0, c0+1
        gload_lds16(ga + c0 * 8,     sa + c0 * 512);
        gload_lds16(ga + c0 * 8 + 8, sa + c0 * 512 + 512);
        gload_lds16(gh + c0 * 8,     sh + c0 * 512);
        gload_lds16(gh + c0 * 8 + 8, sh + c0 * 512 + 512);
    };

    u16 *aCur = sA0, *aNext = sA1, *aNext2 = sA2;
    u16 *hCur = sH0, *hNext = sH1;

    stage(aCur, hCur, part);   // prologue (latency exposed once, overlaps weight preload)
    __syncthreads();

    for (int tile = part; tile < MT; tile += PB) {
        // ---- issue next-tile prefetch FIRST (hidden under this tile's compute) ----
        if (tile + PB < MT) stage(aNext, hNext, tile + PB);

        const u16* sAc = aCur;
        const u16* sHc = hCur;

        f32x4 accR[4], accZ[4], accI[4], accH[4];
#pragma unroll
        for (int mt = 0; mt < 4; ++mt) {
            accR[mt] = (f32x4){0.f, 0.f, 0.f, 0.f};
            accZ[mt] = (f32x4){0.f, 0.f, 0.f, 0.f};
            accI[mt] = (f32x4){0.f, 0.f, 0.f, 0.f};
            accH[mt] = (f32x4){0.f, 0.f, 0.f, 0.f};
        }

        // ---- single merged K-loop: zero global loads inside (weights in VGPRs) ----
#pragma unroll
        for (int ks = 0; ks < 4; ++ks) {
            const int cb = (ks * 4 + quad) << 9;       // chunk base (u16 idx)
#pragma unroll
            for (int mt = 0; mt < 4; ++mt) {
                bf16x8 ag = *(const bf16x8*)&sAc[cb + (mt * 16 + l15) * 8];
                accR[mt] = __builtin_amdgcn_mfma_f32_16x16x32_bf16(ag, fr[ks], accR[mt], 0, 0, 0);
                accZ[mt] = __builtin_amdgcn_mfma_f32_16x16x32_bf16(ag, fz[ks], accZ[mt], 0, 0, 0);
                accI[mt] = __builtin_amdgcn_mfma_f32_16x16x32_bf16(ag, fh[ks], accI[mt], 0, 0, 0);
                accI[mt] = __builtin_amdgcn_mfma_f32_16x16x32_bf16(ag, fl[ks], accI[mt], 0, 0, 0);
                bf16x8 ah = *(const bf16x8*)&sHc[cb + (mt * 16 + l15) * 8];
                accR[mt] = __builtin_amdgcn_mfma_f32_16x16x32_bf16(ah, hr[ks], accR[mt], 0, 0, 0);
                accZ[mt] = __builtin_amdgcn_mfma_f32_16x16x32_bf16(ah, hz[ks], accZ[mt], 0, 0, 0);
                accH[mt] = __builtin_amdgcn_mfma_f32_16x16x32_bf16(ah, hh[ks], accH[mt], 0, 0, 0);
                accH[mt] = __builtin_amdgcn_mfma_f32_16x16x32_bf16(ah, hl[ks], accH[mt], 0, 0, 0);
            }
        }

        // ---- barrier #1: all frag reads done; outstanding vmem (stage, prev
        //      stores) had a full compute phase of head start -> cheap drain ----
        __syncthreads();

        // ---- epilogue: combine -> bf16 into aCur (dead region) ----
#pragma unroll
        for (int mt = 0; mt < 4; ++mt)
#pragma unroll
            for (int r = 0; r < 4; ++r) {
                const int row = mt * 16 + quad * 4 + r;
                const float rr = sigmoidf_(accR[mt][r] + b_r);
                const float zz = sigmoidf_(accZ[mt][r] + b_z);
                const float nn = tanhf_((accI[mt][r] + bin) + rr * (accH[mt][r] + bhn));
                const float hv = bf2f(sHc[cbase + row * 8]);
                aCur[cbase + row * 8] = f2bf((1.0f - zz) * nn + zz * hv);
            }

        // ---- barrier #2: only LDS writes since #1 -> lgkm-only drain, cheap ----
        __syncthreads();

        // ---- async store: drains at a later barrier ----
        const int sgn = tile * 64 + srow;
        if (sgn < N_NODES) {
            uint4 v0 = *(const uint4*)&aCur[(2 * sq) * 512 + srow * 8];
            uint4 v1 = *(const uint4*)&aCur[(2 * sq + 1) * 512 + srow * 8];
            uint4* d = (uint4*)(dst + (size_t)sgn * DIM + sq * 16);
            d[0] = v0; d[1] = v1;
        }

        // rotate buffers: A 3-cycle, H 2-cycle
        u16* ta = aCur; aCur = aNext; aNext = aNext2; aNext2 = ta;
        u16* th = hCur; hCur = hNext; hNext = th;
    }
}

// ---------------- x = (a+b+c)/3 (bf16) ----------------
__global__ void k_avg3(const u16* __restrict__ a, const u16* __restrict__ b,
                       const u16* __restrict__ c, u16* __restrict__ d) {
    const int i = blockIdx.x * 256 + threadIdx.x;
    const uint4 va = ((const uint4*)a)[i];
    const uint4 vb = ((const uint4*)b)[i];
    const uint4 vc = ((const uint4*)c)[i];
    const float third = 1.0f / 3.0f;
    auto comb = [&](uint32_t x, uint32_t y, uint32_t z) -> uint32_t {
        float l = 0.f, h = 0.f;
        unpack_add(x, l, h); unpack_add(y, l, h); unpack_add(z, l, h);
        return packbf(l * third, h * third);
    };
    uint4 vo;
    vo.x = comb(va.x, vb.x, vc.x);
    vo.y = comb(va.y, vb.y, vc.y);
    vo.z = comb(va.z, vb.z, vc.z);
    vo.w = comb(va.w, vb.w, vc.w);
    ((uint4*)d)[i] = vo;
}

// ---------------- pooling (bf16 x) ----------------
__global__ void k_pool(const u16* __restrict__ xf, const int* __restrict__ batch,
                       float* __restrict__ pooled, int* __restrict__ gcnt) {
    const int tid = threadIdx.x;
    const int f = tid & 127;
    const int half = tid >> 7;
    const int nstart = blockIdx.x * 64 + half * 32;
    float accv = 0.0f;
    int curg = -1, cnt = 0;
    for (int t = 0; t < 32; ++t) {
        const int n = nstart + t;
        if (n >= N_NODES) break;
        const int g = batch[n];
        if (g != curg) {
            if (curg >= 0) {
                atomicAdd(&pooled[curg * DIM + f], accv);
                if (f == 0) atomicAdd(&gcnt[curg], cnt);
            }
            curg = g; accv = 0.0f; cnt = 0;
        }
        accv += bf2f(xf[(size_t)n * DIM + f]);
        cnt++;
    }
    if (curg >= 0) {
        atomicAdd(&pooled[curg * DIM + f], accv);
        if (f == 0) atomicAdd(&gcnt[curg], cnt);
    }
}

// ---------------- MLP head: one block per graph ----------------
__global__ void k_head(const float* __restrict__ pooled, const int* __restrict__ gcnt,
                       const float* __restrict__ ptf,
                       const float* __restrict__ fc1w, const float* __restrict__ fc1b,
                       const float* __restrict__ fc2w, const float* __restrict__ fc2b,
                       const float* __restrict__ fclw, const float* __restrict__ fclb,
                       void* __restrict__ out, const int* __restrict__ flag) {
    __shared__ float xh[129];
    __shared__ float h1[80];
    __shared__ float h2[80];
    const int g   = blockIdx.x;
    const int tid = threadIdx.x;

    if (tid < 128) {
        int c = gcnt[g]; if (c < 1) c = 1;
        xh[tid] = pooled[g * 128 + tid] / (float)c;
    }
    if (tid == 0) xh[128] = ptf[g];
    __syncthreads();

    if (tid < 80) {
        float s = fc1b[tid];
        const float* wr = &fc1w[tid * 129];
#pragma unroll 16
        for (int k = 0; k < 129; ++k) s += xh[k] * wr[k];
        h1[tid] = (s > 0.0f) ? s : 0.01f * s;
    }
    __syncthreads();

    if (tid < 80) {
        float s = fc2b[tid];
        const float* wr = &fc2w[tid * 80];
#pragma unroll 16
        for (int k = 0; k < 80; ++k) s += h1[k] * wr[k];
        h2[tid] = (s > 0.0f) ? s : 0.01f * s;
    }
    __syncthreads();

    if (tid < 2) {
        float s = fclb[tid];
        const float* wr = &fclw[tid * 80];
#pragma unroll 16
        for (int k = 0; k < 80; ++k) s += h2[k] * wr[k];
        if (*flag) ((u16*)out)[g * 2 + tid] = f2bf(s);
        else       ((float*)out)[g * 2 + tid] = s;
    }
}

// ---------------- launcher ----------------
extern "C" void kernel_launch(void* const* d_in, const int* in_sizes, int n_in,
                              void* d_out, int out_size, void* d_ws, size_t ws_size,
                              hipStream_t stream) {
    if (n_in < 16) return;
    const void* x_in    = d_in[0];
    const int*  ei      = (const int*)d_in[1];
    const int*  attr    = (const int*)d_in[2];
    const int*  batch   = (const int*)d_in[3];
    const void* pt_in   = d_in[4];
    const void* W_in    = d_in[5];
    const void* wih_in  = d_in[6];
    const void* whh_in  = d_in[7];
    const void* bih_in  = d_in[8];
    const void* bhh_in  = d_in[9];
    const void* fc1w_in = d_in[10];
    const void* fc1b_in = d_in[11];
    const void* fc2w_in = d_in[12];
    const void* fc2b_in = d_in[13];
    const void* fclw_in = d_in[14];
    const void* fclb_in = d_in[15];

    char* ws = (char*)d_ws;
    size_t o = 0;
    auto alloc = [&](size_t b) { size_t r = o; o += (b + 255) & ~(size_t)255; return r; };

    const size_t NB2 = (size_t)N_NODES * DIM * 2;
    const size_t o_flag   = alloc(4);
    const size_t o_xbf    = alloc(NB2);
    const size_t o_A0     = alloc(NB2);
    const size_t o_A1     = alloc(NB2);
    const size_t o_A2     = alloc(NB2);
    const size_t o_B0     = alloc(NB2);
    const size_t o_B1     = alloc(NB2);
    const size_t o_Wt     = alloc((size_t)NSETS * NLAYERS * DIM * DIM * 4);
    const size_t o_Wf_hi  = alloc((size_t)NSETS * NLAYERS * 384 * DIM * 2);
    const size_t o_Wf_lo  = alloc((size_t)NSETS * NLAYERS * 384 * DIM * 2);
    const size_t o_whh_hi = alloc((size_t)NSETS * 384 * DIM * 2);
    const size_t o_whh_lo = alloc((size_t)NSETS * 384 * DIM * 2);
    const size_t o_bih    = alloc((size_t)NSETS * 384 * 4);
    const size_t o_bhh    = alloc((size_t)NSETS * 384 * 4);
    const size_t o_fc1w   = alloc(10320 * 4);
    const size_t o_fc1b   = alloc(80 * 4);
    const size_t o_fc2w   = alloc(6400 * 4);
    const size_t o_fc2b   = alloc(80 * 4);
    const size_t o_fclw   = alloc(160 * 4);
    const size_t o_fclb   = alloc(2 * 4);
    const size_t o_ptf    = alloc(64 * 4);
    const size_t o_cnt    = alloc(((size_t)3 * N_NODES + 1) * 4);
    const size_t o_cursor = alloc((size_t)3 * N_NODES * 4);
    const size_t o_col    = alloc((size_t)N_EDGES * 4);
    const int    nb_scan  = (3 * N_NODES + 1023) / 1024;
    const size_t o_part   = alloc((size_t)nb_scan * 4);
    const size_t o_pooled = alloc((size_t)NGRAPH * DIM * 4);
    const size_t o_gcnt   = alloc((size_t)NGRAPH * 4);

    if (ws_size < o) {
        fprintf(stderr, "GGNN kernel: workspace too small: need %zu, have %zu\n", o, ws_size);
        return;
    }

    int*   flag   = (int*)(ws + o_flag);
    u16*   xbf    = (u16*)(ws + o_xbf);
    u16*   A0     = (u16*)(ws + o_A0);
    u16*   A1     = (u16*)(ws + o_A1);
    u16*   A2     = (u16*)(ws + o_A2);
    u16*   B0     = (u16*)(ws + o_B0);
    u16*   B1     = (u16*)(ws + o_B1);
    float* Wt     = (float*)(ws + o_Wt);
    u16*   Wf_hi  = (u16*)(ws + o_Wf_hi);
    u16*   Wf_lo  = (u16*)(ws + o_Wf_lo);
    u16*   whh_hi = (u16*)(ws + o_whh_hi);
    u16*   whh_lo = (u16*)(ws + o_whh_lo);
    float* bihf   = (float*)(ws + o_bih);
    float* bhhf   = (float*)(ws + o_bhh);
    float* fc1wf  = (float*)(ws + o_fc1w);
    float* fc1bf  = (float*)(ws + o_fc1b);
    float* fc2wf  = (float*)(ws + o_fc2w);
    float* fc2bf  = (float*)(ws + o_fc2b);
    float* fclwf  = (float*)(ws + o_fclw);
    float* fclbf  = (float*)(ws + o_fclb);
    float* ptf    = (float*)(ws + o_ptf);
    int*   cnt    = (int*)(ws + o_cnt);
    int*   rp     = cnt;
    int*   cursor = (int*)(ws + o_cursor);
    int*   col    = (int*)(ws + o_col);
    int*   part   = (int*)(ws + o_part);
    float* pooled = (float*)(ws + o_pooled);
    int*   gcnt   = (int*)(ws + o_gcnt);

    hipMemsetAsync(cnt, 0, (size_t)3 * N_NODES * 4, stream);
    hipMemsetAsync(pooled, 0, (o_gcnt - o_pooled) + (size_t)NGRAPH * 4, stream);

    k_detect<<<1, 256, 0, stream>>>((const u16*)x_in, flag);

    // converts + weight prep (coalesced transW+fuse restored; 9 small converts merged)
    k_to_bf<<<(N_NODES * DIM + 2047) / 2048, 256, 0, stream>>>(x_in, xbf, N_NODES * DIM, flag);
    k_transW<<<(NSETS * NLAYERS * DIM * DIM + 255) / 256, 256, 0, stream>>>(W_in, Wt, flag);
    k_fuse<<<(NSETS * NLAYERS * 384 * DIM) / 256, 256, 0, stream>>>(Wt, wih_in, Wf_hi, Wf_lo, flag);
    k_prep_G<<<(NSETS * 384 * DIM + 255) / 256, 256, 0, stream>>>(whh_in, whh_hi, whh_lo, flag);
    k_convsmall<<<(19410 + 255) / 256, 256, 0, stream>>>(
        bih_in, bhh_in, fc1w_in, fc1b_in, fc2w_in, fc2b_in, fclw_in, fclb_in, pt_in,
        bihf, bhhf, fc1wf, fc1bf, fc2wf, fc2bf, fclwf, fclbf, ptf, flag);

    // CSR build
    k_deg<<<(N_EDGES + 255) / 256, 256, 0, stream>>>(ei, attr, cnt);
    k_scan1<<<nb_scan, 1024, 0, stream>>>(cnt, rp, part, 3 * N_NODES);
    k_scan2<<<1, 1024, 0, stream>>>(part, nb_scan);
    k_scan3<<<nb_scan, 1024, 0, stream>>>(rp, cursor, part, 3 * N_NODES);
    k_fill<<<(N_EDGES + 255) / 256, 256, 0, stream>>>(ei, attr, cursor, col);

    // GGC passes (split gather + persistent weight-resident gemm)
    for (int pass = 0; pass < NPASS; ++pass) {
        k_gather<<<3 * GT, 256, 0, stream>>>(xbf, xbf, xbf, A0, A1, A2, rp, col);
        k_gemm<<<3 * PB, 512, 0, stream>>>(A0, A1, A2, xbf, xbf, xbf, A0, A1, A2,
                                           Wf_hi, Wf_lo, whh_hi, whh_lo, bihf, bhhf, 0);
        k_gather<<<3 * GT, 256, 0, stream>>>(A0, A1, A2, B0, B1, xbf, rp, col);
        k_gemm<<<3 * PB, 512, 0, stream>>>(B0, B1, xbf, A0, A1, A2, A0, A1, A2,
                                           Wf_hi, Wf_lo, whh_hi, whh_lo, bihf, bhhf, 1);
        k_avg3<<<(N_NODES * DIM / 8) / 256, 256, 0, stream>>>(A0, A1, A2, xbf);
    }

    // pooling + head (one block per graph)
    k_pool<<<MT, 256, 0, stream>>>(xbf, batch, pooled, gcnt);
    k_head<<<NGRAPH, 128, 0, stream>>>(pooled, gcnt, ptf, fc1wf, fc1bf, fc2wf, fc2bf,
                                       fclwf, fclbf, d_out, flag);
}

// Round 11
// 779.467 us; speedup vs baseline: 1.1072x; 1.0282x over previous
//
#include <hip/hip_runtime.h>
#include <cstdio>
#include <cstdint>

#define N_NODES 100000
#define N_EDGES 600000
#define DIM     128
#define NSETS   3
#define NLAYERS 2
#define NGRAPH  64
#define NPASS   2
#define GT      3125      // gather tiles (32 nodes each)
#define MT      1563      // node tiles (64 nodes each)  -- also k_pool grid
#define PB      85        // persistent gemm blocks per set (3*PB = 255 <= 256 CUs, 1 block/CU)

// mega-prep block ranges
#define PREP_TOBF   6250                  // to_bf: 12.8M elems, grid-stride
#define PREP_TRANSW (PREP_TOBF + 384)     // transW: 98304 elems
#define PREP_PREPG  (PREP_TRANSW + 576)   // prep_G: 147456 elems
#define PREP_CONV   (PREP_PREPG + 76)     // convsmall: 19410 elems
#define PREP_BLOCKS PREP_CONV

typedef __bf16 bf16x8 __attribute__((ext_vector_type(8)));
typedef float  f32x4  __attribute__((ext_vector_type(4)));
typedef unsigned short u16;

static __device__ __forceinline__ float bf2f(u16 u) {
    return __uint_as_float(((uint32_t)u) << 16);
}
// native RNE f32->bf16 (compiler emits v_cvt_pk_bf16_f32; same rounding as manual RNE)
static __device__ __forceinline__ u16 f2bf(float f) {
    union { __bf16 b; u16 u; } c;
    c.b = (__bf16)f;
    return c.u;
}
static __device__ __forceinline__ uint32_t packbf(float lo, float hi) {
    return (uint32_t)f2bf(lo) | ((uint32_t)f2bf(hi) << 16);
}
static __device__ __forceinline__ void unpack_add(uint32_t u, float& a0, float& a1) {
    a0 += __uint_as_float(u << 16);
    a1 += __uint_as_float(u & 0xFFFF0000u);
}
static __device__ __forceinline__ float fast_rcp(float x) {
    return __builtin_amdgcn_rcpf(x);
}
static __device__ __forceinline__ float sigmoidf_(float x) {
    return fast_rcp(1.0f + __expf(-x));
}
static __device__ __forceinline__ float tanhf_(float x) {
    return 1.0f - 2.0f * fast_rcp(__expf(2.0f * x) + 1.0f);
}

// async global->LDS, 16 B per lane; LDS dest = wave-uniform base + lane*16
static __device__ __forceinline__ void gload_lds16(const u16* g, u16* l) {
    __builtin_amdgcn_global_load_lds(
        (const __attribute__((address_space(1))) void*)g,
        (__attribute__((address_space(3))) void*)l, 16, 0, 0);
}

// ---------------- dtype detection ----------------
__global__ void k_detect(const u16* __restrict__ x, int* __restrict__ flag) {
    __shared__ float red[256];
    float m = 0.0f;
    for (int i = threadIdx.x; i < 8192; i += 256) {
        float f = __uint_as_float(((uint32_t)x[i]) << 16);
        f = fabsf(f);
        if (isnan(f)) f = 3.0e38f;
        m = fmaxf(m, f);
    }
    red[threadIdx.x] = m;
    __syncthreads();
    for (int off = 128; off > 0; off >>= 1) {
        if (threadIdx.x < off) red[threadIdx.x] = fmaxf(red[threadIdx.x], red[threadIdx.x + off]);
        __syncthreads();
    }
    if (threadIdx.x == 0) flag[0] = (red[0] < 1.0e6f) ? 1 : 0;
}

// ---------------- mega-prep: to_bf | transW | prep_G | convsmall in ONE launch ----------------
// All four sections are mutually independent (distinct outputs); bodies are
// verbatim copies of the round-10 kernels -> bit-identical results. The three
// small sections hide under to_bf's bandwidth phase instead of running as
// serial launches.
__global__ void k_prep(const void* __restrict__ x_in, u16* __restrict__ xbf,
                       const void* __restrict__ W_in, float* __restrict__ Wt,
                       const void* __restrict__ whh_in, u16* __restrict__ g_hi, u16* __restrict__ g_lo,
                       const void* __restrict__ b0, const void* __restrict__ b1,
                       const void* __restrict__ w1, const void* __restrict__ c1,
                       const void* __restrict__ w2, const void* __restrict__ c2,
                       const void* __restrict__ wl, const void* __restrict__ cl,
                       const void* __restrict__ pt,
                       float* __restrict__ d_b0, float* __restrict__ d_b1,
                       float* __restrict__ d_w1, float* __restrict__ d_c1,
                       float* __restrict__ d_w2, float* __restrict__ d_c2,
                       float* __restrict__ d_wl, float* __restrict__ d_cl,
                       float* __restrict__ d_pt,
                       const int* __restrict__ flag) {
    const int f = *flag;
    const int b = blockIdx.x;
    if (b < PREP_TOBF) {
        // ---- x -> bf16 (grid-stride, 6250 blocks) ----
        const int n = N_NODES * DIM;
        for (int i = b * 256 + threadIdx.x; i < n; i += PREP_TOBF * 256) {
            if (f) xbf[i] = ((const u16*)x_in)[i];
            else   xbf[i] = f2bf(((const float*)x_in)[i]);
        }
    } else if (b < PREP_TRANSW) {
        // ---- W raw [S][L][j][d] -> Wt fp32 [sl][d][j] (coalesced-fuse prep) ----
        const int i = (b - PREP_TOBF) * 256 + threadIdx.x;   // 384*256 == 98304 exactly
        const int sl = i >> 14;
        const int rem = i & 16383;
        const int d = rem >> 7;
        const int j = rem & 127;
        const int si = (sl << 14) + j * 128 + d;
        float v;
        if (f) v = bf2f(((const u16*)W_in)[si]);
        else   v = ((const float*)W_in)[si];
        Wt[i] = v;
    } else if (b < PREP_PREPG) {
        // ---- whh -> hi/lo bf16 ----
        const int i = (b - PREP_TRANSW) * 256 + threadIdx.x; // 576*256 == 147456 exactly
        float v;
        if (f) v = bf2f(((const u16*)whh_in)[i]);
        else   v = ((const float*)whh_in)[i];
        u16 h = f2bf(v);
        g_hi[i] = h;
        g_lo[i] = f2bf(v - bf2f(h));
    } else {
        // ---- 9 small fp32 conversions ----
        const int i = (b - PREP_PREPG) * 256 + threadIdx.x;
        const void* src; float* dst; int off;
        if      (i < 1152)  { src = b0; dst = d_b0; off = i; }
        else if (i < 2304)  { src = b1; dst = d_b1; off = i - 1152; }
        else if (i < 12624) { src = w1; dst = d_w1; off = i - 2304; }
        else if (i < 12704) { src = c1; dst = d_c1; off = i - 12624; }
        else if (i < 19104) { src = w2; dst = d_w2; off = i - 12704; }
        else if (i < 19184) { src = c2; dst = d_c2; off = i - 19104; }
        else if (i < 19344) { src = wl; dst = d_wl; off = i - 19184; }
        else if (i < 19346) { src = cl; dst = d_cl; off = i - 19344; }
        else if (i < 19410) { src = pt; dst = d_pt; off = i - 19346; }
        else return;
        float v;
        if (f) v = bf2f(((const u16*)src)[off]);
        else   v = ((const float*)src)[off];
        dst[off] = v;
    }
}

// Wf[sl][n][j] = sum_d wih[s][n][d] * Wt[sl][d][j]
__global__ void k_fuse(const float* __restrict__ Wt, const void* __restrict__ wih_raw,
                       u16* __restrict__ hi, u16* __restrict__ lo,
                       const int* __restrict__ flag) {
    const int f = *flag;
    const int i = blockIdx.x * 256 + threadIdx.x;
    const int sl = i / 49152;
    const int rem = i - sl * 49152;
    const int n = rem >> 7;
    const int j = rem & 127;
    const int s = sl >> 1;
    const float* wt = Wt + (sl << 14) + j;
    const int wb = (s * 384 + n) * 128;
    float acc = 0.0f;
#pragma unroll 8
    for (int d = 0; d < 128; ++d) {
        float wv;
        if (f) wv = bf2f(((const u16*)wih_raw)[wb + d]);
        else   wv = ((const float*)wih_raw)[wb + d];
        acc = fmaf(wv, wt[d * 128], acc);
    }
    u16 h = f2bf(acc);
    hi[i] = h;
    lo[i] = f2bf(acc - bf2f(h));
}

// ---------------- CSR build ----------------
__global__ void k_deg(const int* __restrict__ ei, const int* __restrict__ attr,
                      int* __restrict__ cnt) {
    int e = blockIdx.x * 256 + threadIdx.x;
    if (e < N_EDGES) {
        int t = attr[e];
        int d = ei[N_EDGES + e];
        atomicAdd(&cnt[t * N_NODES + d], 1);
    }
}

__global__ void k_scan1(const int* __restrict__ cnt, int* __restrict__ rp,
                        int* __restrict__ part, int n) {
    __shared__ int buf[1024];
    int gid = blockIdx.x * 1024 + threadIdx.x;
    int v = (gid < n) ? cnt[gid] : 0;
    buf[threadIdx.x] = v;
    __syncthreads();
    for (int off = 1; off < 1024; off <<= 1) {
        int t = (threadIdx.x >= off) ? buf[threadIdx.x - off] : 0;
        __syncthreads();
        buf[threadIdx.x] += t;
        __syncthreads();
    }
    if (gid < n) rp[gid] = buf[threadIdx.x] - v;
    if (threadIdx.x == 1023) part[blockIdx.x] = buf[1023];
}

__global__ void k_scan2(int* __restrict__ part, int nb) {
    __shared__ int buf[1024];
    int v = (threadIdx.x < nb) ? part[threadIdx.x] : 0;
    buf[threadIdx.x] = v;
    __syncthreads();
    for (int off = 1; off < 1024; off <<= 1) {
        int t = (threadIdx.x >= off) ? buf[threadIdx.x - off] : 0;
        __syncthreads();
        buf[threadIdx.x] += t;
        __syncthreads();
    }
    if (threadIdx.x < nb) part[threadIdx.x] = buf[threadIdx.x] - v;
}

__global__ void k_scan3(int* __restrict__ rp, int* __restrict__ cursor,
                        const int* __restrict__ part, int n) {
    int gid = blockIdx.x * 1024 + threadIdx.x;
    if (gid < n) {
        int v = rp[gid] + part[blockIdx.x];
        rp[gid] = v;
        cursor[gid] = v;
    }
    if (gid == 0) rp[n] = N_EDGES;
}

__global__ void k_fill(const int* __restrict__ ei, const int* __restrict__ attr,
                       int* __restrict__ cursor, int* __restrict__ col) {
    int e = blockIdx.x * 256 + threadIdx.x;
    if (e < N_EDGES) {
        int t = attr[e];
        int d = ei[N_EDGES + e];
        int s = ei[e];
        int pos = atomicAdd(&cursor[t * N_NODES + d], 1);
        col[pos] = s;
    }
}

// ---------------- gather (standalone: 6 blocks/CU hides the 3-deep load chain) ----------------
__global__ void __launch_bounds__(256, 6)
k_gather(const u16* __restrict__ s0, const u16* __restrict__ s1, const u16* __restrict__ s2,
         u16* __restrict__ d0, u16* __restrict__ d1, u16* __restrict__ d2,
         const int* __restrict__ rp, const int* __restrict__ colarr) {
    const int bx = blockIdx.x;
    const int set = bx / GT;
    const int tile = bx - set * GT;
    const u16* __restrict__ src = (set == 0) ? s0 : (set == 1) ? s1 : s2;
    u16* __restrict__ dst = (set == 0) ? d0 : (set == 1) ? d1 : d2;
    const int* __restrict__ rp_s = rp + set * N_NODES;

    const int nl = threadIdx.x >> 3;
    const int q  = threadIdx.x & 7;
    const int gn = tile * 32 + nl;

    float a[16];
#pragma unroll
    for (int j = 0; j < 16; ++j) a[j] = 0.0f;

    const int beg = rp_s[gn], end = rp_s[gn + 1];
    int dg = end - beg; if (dg < 1) dg = 1;
    const float inv = 1.0f / (float)dg;

    int e = beg;
    for (; e + 2 <= end; e += 2) {
        const int c0 = colarr[e];
        const int c1 = colarr[e + 1];
        const uint4* m0 = (const uint4*)(src + (size_t)c0 * DIM + q * 16);
        const uint4* m1 = (const uint4*)(src + (size_t)c1 * DIM + q * 16);
        uint4 v0 = m0[0], v1 = m0[1], w0 = m1[0], w1 = m1[1];
        unpack_add(v0.x, a[0], a[1]);   unpack_add(v0.y, a[2], a[3]);
        unpack_add(v0.z, a[4], a[5]);   unpack_add(v0.w, a[6], a[7]);
        unpack_add(v1.x, a[8], a[9]);   unpack_add(v1.y, a[10], a[11]);
        unpack_add(v1.z, a[12], a[13]); unpack_add(v1.w, a[14], a[15]);
        unpack_add(w0.x, a[0], a[1]);   unpack_add(w0.y, a[2], a[3]);
        unpack_add(w0.z, a[4], a[5]);   unpack_add(w0.w, a[6], a[7]);
        unpack_add(w1.x, a[8], a[9]);   unpack_add(w1.y, a[10], a[11]);
        unpack_add(w1.z, a[12], a[13]); unpack_add(w1.w, a[14], a[15]);
    }
    if (e < end) {
        const int c0 = colarr[e];
        const uint4* m0 = (const uint4*)(src + (size_t)c0 * DIM + q * 16);
        uint4 v0 = m0[0], v1 = m0[1];
        unpack_add(v0.x, a[0], a[1]);   unpack_add(v0.y, a[2], a[3]);
        unpack_add(v0.z, a[4], a[5]);   unpack_add(v0.w, a[6], a[7]);
        unpack_add(v1.x, a[8], a[9]);   unpack_add(v1.y, a[10], a[11]);
        unpack_add(v1.z, a[12], a[13]); unpack_add(v1.w, a[14], a[15]);
    }
#pragma unroll
    for (int j = 0; j < 16; ++j) a[j] *= inv;

    uint4* d = (uint4*)(dst + (size_t)gn * DIM + q * 16);
    d[0] = make_uint4(packbf(a[0], a[1]), packbf(a[2], a[3]),
                      packbf(a[4], a[5]), packbf(a[6], a[7]));
    d[1] = make_uint4(packbf(a[8], a[9]), packbf(a[10], a[11]),
                      packbf(a[12], a[13]), packbf(a[14], a[15]));
}

// ---------------- persistent fused GEMM+GRU: weights VGPR-resident ----------------
// Round-7 measured-known-good version (~103us/dispatch). Each wave preloads
// its full weight set ONCE (32 bf16x8 = 128 VGPR), eliminating the
// per-iteration L2 weight re-stream. 1 block/CU (grid 3*85=255), ~18
// tiles/block, merged A/H K-loop, A triple-buffered / H double-buffered LDS
// (80KB), stage via global_load_lds, stores issued after bar#2 and drained at
// the next iteration's loop-top barrier. Structure floor: ~190 unified
// regs/wave forbids >2 waves/SIMD; same-block waves are barrier-locked, so
// MFMA and epilogue-VALU phases serialize (measured ~80% of that floor).
__global__ void __launch_bounds__(512, 2)
k_gemm(const u16* __restrict__ g0, const u16* __restrict__ g1, const u16* __restrict__ g2,
       const u16* __restrict__ o0, const u16* __restrict__ o1, const u16* __restrict__ o2,
       u16* __restrict__ d0, u16* __restrict__ d1, u16* __restrict__ d2,
       const u16* __restrict__ Wf_hi, const u16* __restrict__ Wf_lo,
       const u16* __restrict__ whh_hi, const u16* __restrict__ whh_lo,
       const float* __restrict__ bih, const float* __restrict__ bhh, int layer)
{
    __shared__ u16 sA0[16 * 512], sA1[16 * 512], sA2[16 * 512];   // agg: triple buffer
    __shared__ u16 sH0[16 * 512], sH1[16 * 512];                  // own h: double buffer

    const int tid  = threadIdx.x;
    const int lane = tid & 63;
    const int wv   = tid >> 6;        // 0..7
    const int l15  = lane & 15;
    const int quad = lane >> 4;
    const int col  = wv * 16 + l15;   // this lane's output column

    const int set  = blockIdx.x / PB;
    const int part = blockIdx.x - set * PB;

    const u16* __restrict__ gsrc = (set == 0) ? g0 : (set == 1) ? g1 : g2;
    const u16* __restrict__ osrc = (set == 0) ? o0 : (set == 1) ? o1 : o2;
    u16* __restrict__ dst        = (set == 0) ? d0 : (set == 1) ? d1 : d2;
    const u16* wf_hi = Wf_hi + (size_t)(set * NLAYERS + layer) * 384 * DIM;
    const u16* wf_lo = Wf_lo + (size_t)(set * NLAYERS + layer) * 384 * DIM;
    const u16* wh_hi = whh_hi + (size_t)set * 384 * DIM;
    const u16* wh_lo = whh_lo + (size_t)set * 384 * DIM;
    const float* bi_s = bih + (size_t)set * 384;
    const float* bh_s = bhh + (size_t)set * 384;

    // store coords: 64 rows x 8 chunk-pairs of 32 B
    const int srow = tid >> 3;
    const int sq   = tid & 7;

    // biases for this lane's column
    const float b_r = bi_s[col] + bh_s[col];
    const float b_z = bi_s[128 + col] + bh_s[128 + col];
    const float bin = bi_s[256 + col];
    const float bhn = bh_s[256 + col];

    // weight row offsets (u16 elements)
    const int pr = col * 128 + quad * 8;
    const int pz = (128 + col) * 128 + quad * 8;
    const int pn = (256 + col) * 128 + quad * 8;

    // ---- preload ALL weights into registers (32 x bf16x8 = 128 VGPR) ----
    bf16x8 fr[4], fz[4], fh[4], fl[4], hr[4], hz[4], hh[4], hl[4];
#pragma unroll
    for (int ks = 0; ks < 4; ++ks) {
        const int k0 = ks * 32;
        fr[ks] = *(const bf16x8*)(wf_hi + pr + k0);
        fz[ks] = *(const bf16x8*)(wf_hi + pz + k0);
        fh[ks] = *(const bf16x8*)(wf_hi + pn + k0);
        fl[ks] = *(const bf16x8*)(wf_lo + pn + k0);
        hr[ks] = *(const bf16x8*)(wh_hi + pr + k0);
        hz[ks] = *(const bf16x8*)(wh_hi + pz + k0);
        hh[ks] = *(const bf16x8*)(wh_hi + pn + k0);
        hl[ks] = *(const bf16x8*)(wh_lo + pn + k0);
    }

    // chunk-major u16 index base for this lane's column (epilogue/hv)
    const int cbase = ((col >> 3) << 9) + (col & 7);   // chunk*512 + within-chunk

    // stage one 64-row tile of A and H into chunk-major LDS (4 gload_lds16/wave)
    auto stage = [&](u16* sa, u16* sh, int tile) {
        int nn = tile * 64 + lane;
        if (nn >= N_NODES) nn = N_NODES - 1;           // tail rows: garbage, never stored
        const u16* ga = gsrc + (size_t)nn * DIM;
        const u16* gh = osrc + (size_t)nn * DIM;
        const int c0 = wv * 2;                         // wave handles chunks c0, c0+1
        gload_lds16(ga + c0 * 8,     sa + c0 * 512);
        gload_lds16(ga + c0 * 8 + 8, sa + c0 * 512 + 512);
        gload_lds16(gh + c0 * 8,     sh + c0 * 512);
        gload_lds16(gh + c0 * 8 + 8, sh + c0 * 512 + 512);
    };

    u16 *aCur = sA0, *aNext = sA1, *aNext2 = sA2;
    u16 *hCur = sH0, *hNext = sH1;

    stage(aCur, hCur, part);   // prologue (latency exposed once, overlaps weight preload)
    __syncthreads();

    for (int tile = part; tile < MT; tile += PB) {
        // ---- issue next-tile prefetch FIRST (hidden under this tile's compute) ----
        if (tile + PB < MT) stage(aNext, hNext, tile + PB);

        const u16* sAc = aCur;
        const u16* sHc = hCur;

        f32x4 accR[4], accZ[4], accI[4], accH[4];
#pragma unroll
        for (int mt = 0; mt < 4; ++mt) {
            accR[mt] = (f32x4){0.f, 0.f, 0.f, 0.f};
            accZ[mt] = (f32x4){0.f, 0.f, 0.f, 0.f};
            accI[mt] = (f32x4){0.f, 0.f, 0.f, 0.f};
            accH[mt] = (f32x4){0.f, 0.f, 0.f, 0.f};
        }

        // ---- single merged K-loop: zero global loads inside (weights in VGPRs) ----
#pragma unroll
        for (int ks = 0; ks < 4; ++ks) {
            const int cb = (ks * 4 + quad) << 9;       // chunk base (u16 idx)
#pragma unroll
            for (int mt = 0; mt < 4; ++mt) {
                bf16x8 ag = *(const bf16x8*)&sAc[cb + (mt * 16 + l15) * 8];
                accR[mt] = __builtin_amdgcn_mfma_f32_16x16x32_bf16(ag, fr[ks], accR[mt], 0, 0, 0);
                accZ[mt] = __builtin_amdgcn_mfma_f32_16x16x32_bf16(ag, fz[ks], accZ[mt], 0, 0, 0);
                accI[mt] = __builtin_amdgcn_mfma_f32_16x16x32_bf16(ag, fh[ks], accI[mt], 0, 0, 0);
                accI[mt] = __builtin_amdgcn_mfma_f32_16x16x32_bf16(ag, fl[ks], accI[mt], 0, 0, 0);
                bf16x8 ah = *(const bf16x8*)&sHc[cb + (mt * 16 + l15) * 8];
                accR[mt] = __builtin_amdgcn_mfma_f32_16x16x32_bf16(ah, hr[ks], accR[mt], 0, 0, 0);
                accZ[mt] = __builtin_amdgcn_mfma_f32_16x16x32_bf16(ah, hz[ks], accZ[mt], 0, 0, 0);
                accH[mt] = __builtin_amdgcn_mfma_f32_16x16x32_bf16(ah, hh[ks], accH[mt], 0, 0, 0);
                accH[mt] = __builtin_amdgcn_mfma_f32_16x16x32_bf16(ah, hl[ks], accH[mt], 0, 0, 0);
            }
        }

        // ---- barrier #1: all frag reads done; outstanding vmem (stage, prev
        //      stores) had a full compute phase of head start -> cheap drain ----
        __syncthreads();

        // ---- epilogue: combine -> bf16 into aCur (dead region) ----
#pragma unroll
        for (int mt = 0; mt < 4; ++mt)
#pragma unroll
            for (int r = 0; r < 4; ++r) {
                const int row = mt * 16 + quad * 4 + r;
                const float rr = sigmoidf_(accR[mt][r] + b_r);
                const float zz = sigmoidf_(accZ[mt][r] + b_z);
                const float nn = tanhf_((accI[mt][r] + bin) + rr * (accH[mt][r] + bhn));
                const float hv = bf2f(sHc[cbase + row * 8]);
                aCur[cbase + row * 8] = f2bf((1.0f - zz) * nn + zz * hv);
            }

        // ---- barrier #2: only LDS writes since #1 -> lgkm-only drain, cheap ----
        __syncthreads();

        // ---- async store: drains at a later barrier ----
        const int sgn = tile * 64 + srow;
        if (sgn < N_NODES) {
            uint4 v0 = *(const uint4*)&aCur[(2 * sq) * 512 + srow * 8];
            uint4 v1 = *(const uint4*)&aCur[(2 * sq + 1) * 512 + srow * 8];
            uint4* d = (uint4*)(dst + (size_t)sgn * DIM + sq * 16);
            d[0] = v0; d[1] = v1;
        }

        // rotate buffers: A 3-cycle, H 2-cycle
        u16* ta = aCur; aCur = aNext; aNext = aNext2; aNext2 = ta;
        u16* th = hCur; hCur = hNext; hNext = th;
    }
}

// ---------------- x = (a+b+c)/3 (bf16) ----------------
__global__ void k_avg3(const u16* __restrict__ a, const u16* __restrict__ b,
                       const u16* __restrict__ c, u16* __restrict__ d) {
    const int i = blockIdx.x * 256 + threadIdx.x;
    const uint4 va = ((const uint4*)a)[i];
    const uint4 vb = ((const uint4*)b)[i];
    const uint4 vc = ((const uint4*)c)[i];
    const float third = 1.0f / 3.0f;
    auto comb = [&](uint32_t x, uint32_t y, uint32_t z) -> uint32_t {
        float l = 0.f, h = 0.f;
        unpack_add(x, l, h); unpack_add(y, l, h); unpack_add(z, l, h);
        return packbf(l * third, h * third);
    };
    uint4 vo;
    vo.x = comb(va.x, vb.x, vc.x);
    vo.y = comb(va.y, vb.y, vc.y);
    vo.z = comb(va.z, vb.z, vc.z);
    vo.w = comb(va.w, vb.w, vc.w);
    ((uint4*)d)[i] = vo;
}

// ---------------- pooling fused with final avg3: reads the 3 set outputs and
// averages with the SAME bf16 round-trip as k_avg3 (f2bf->bf2f before
// accumulate) -> bit-identical to avg3-then-pool. Saves one dispatch and the
// xbf write+read round-trip. ----------------
__global__ void k_pool3(const u16* __restrict__ xa, const u16* __restrict__ xb,
                        const u16* __restrict__ xc, const int* __restrict__ batch,
                        float* __restrict__ pooled, int* __restrict__ gcnt) {
    const int tid = threadIdx.x;
    const int f = tid & 127;
    const int half = tid >> 7;
    const int nstart = blockIdx.x * 64 + half * 32;
    const float third = 1.0f / 3.0f;
    float accv = 0.0f;
    int curg = -1, cnt = 0;
    for (int t = 0; t < 32; ++t) {
        const int n = nstart + t;
        if (n >= N_NODES) break;
        const int g = batch[n];
        if (g != curg) {
            if (curg >= 0) {
                atomicAdd(&pooled[curg * DIM + f], accv);
                if (f == 0) atomicAdd(&gcnt[curg], cnt);
            }
            curg = g; accv = 0.0f; cnt = 0;
        }
        const size_t idx = (size_t)n * DIM + f;
        const float s = bf2f(xa[idx]) + bf2f(xb[idx]) + bf2f(xc[idx]);
        accv += bf2f(f2bf(s * third));   // bf16 round-trip: matches k_avg3 exactly
        cnt++;
    }
    if (curg >= 0) {
        atomicAdd(&pooled[curg * DIM + f], accv);
        if (f == 0) atomicAdd(&gcnt[curg], cnt);
    }
}

// ---------------- MLP head: one block per graph ----------------
__global__ void k_head(const float* __restrict__ pooled, const int* __restrict__ gcnt,
                       const float* __restrict__ ptf,
                       const float* __restrict__ fc1w, const float* __restrict__ fc1b,
                       const float* __restrict__ fc2w, const float* __restrict__ fc2b,
                       const float* __restrict__ fclw, const float* __restrict__ fclb,
                       void* __restrict__ out, const int* __restrict__ flag) {
    __shared__ float xh[129];
    __shared__ float h1[80];
    __shared__ float h2[80];
    const int g   = blockIdx.x;
    const int tid = threadIdx.x;

    if (tid < 128) {
        int c = gcnt[g]; if (c < 1) c = 1;
        xh[tid] = pooled[g * 128 + tid] / (float)c;
    }
    if (tid == 0) xh[128] = ptf[g];
    __syncthreads();

    if (tid < 80) {
        float s = fc1b[tid];
        const float* wr = &fc1w[tid * 129];
#pragma unroll 16
        for (int k = 0; k < 129; ++k) s += xh[k] * wr[k];
        h1[tid] = (s > 0.0f) ? s : 0.01f * s;
    }
    __syncthreads();

    if (tid < 80) {
        float s = fc2b[tid];
        const float* wr = &fc2w[tid * 80];
#pragma unroll 16
        for (int k = 0; k < 80; ++k) s += h1[k] * wr[k];
        h2[tid] = (s > 0.0f) ? s : 0.01f * s;
    }
    __syncthreads();

    if (tid < 2) {
        float s = fclb[tid];
        const float* wr = &fclw[tid * 80];
#pragma unroll 16
        for (int k = 0; k < 80; ++k) s += h2[k] * wr[k];
        if (*flag) ((u16*)out)[g * 2 + tid] = f2bf(s);
        else       ((float*)out)[g * 2 + tid] = s;
    }
}

// ---------------- launcher ----------------
extern "C" void kernel_launch(void* const* d_in, const int* in_sizes, int n_in,
                              void* d_out, int out_size, void* d_ws, size_t ws_size,
                              hipStream_t stream) {
    if (n_in < 16) return;
    const void* x_in    = d_in[0];
    const int*  ei      = (const int*)d_in[1];
    const int*  attr    = (const int*)d_in[2];
    const int*  batch   = (const int*)d_in[3];
    const void* pt_in   = d_in[4];
    const void* W_in    = d_in[5];
    const void* wih_in  = d_in[6];
    const void* whh_in  = d_in[7];
    const void* bih_in  = d_in[8];
    const void* bhh_in  = d_in[9];
    const void* fc1w_in = d_in[10];
    const void* fc1b_in = d_in[11];
    const void* fc2w_in = d_in[12];
    const void* fc2b_in = d_in[13];
    const void* fclw_in = d_in[14];
    const void* fclb_in = d_in[15];

    char* ws = (char*)d_ws;
    size_t o = 0;
    auto alloc = [&](size_t b) { size_t r = o; o += (b + 255) & ~(size_t)255; return r; };

    const size_t NB2 = (size_t)N_NODES * DIM * 2;
    const size_t o_flag   = alloc(4);
    const size_t o_xbf    = alloc(NB2);
    const size_t o_A0     = alloc(NB2);
    const size_t o_A1     = alloc(NB2);
    const size_t o_A2     = alloc(NB2);
    const size_t o_B0     = alloc(NB2);
    const size_t o_B1     = alloc(NB2);
    const size_t o_Wt     = alloc((size_t)NSETS * NLAYERS * DIM * DIM * 4);
    const size_t o_Wf_hi  = alloc((size_t)NSETS * NLAYERS * 384 * DIM * 2);
    const size_t o_Wf_lo  = alloc((size_t)NSETS * NLAYERS * 384 * DIM * 2);
    const size_t o_whh_hi = alloc((size_t)NSETS * 384 * DIM * 2);
    const size_t o_whh_lo = alloc((size_t)NSETS * 384 * DIM * 2);
    const size_t o_bih    = alloc((size_t)NSETS * 384 * 4);
    const size_t o_bhh    = alloc((size_t)NSETS * 384 * 4);
    const size_t o_fc1w   = alloc(10320 * 4);
    const size_t o_fc1b   = alloc(80 * 4);
    const size_t o_fc2w   = alloc(6400 * 4);
    const size_t o_fc2b   = alloc(80 * 4);
    const size_t o_fclw   = alloc(160 * 4);
    const size_t o_fclb   = alloc(2 * 4);
    const size_t o_ptf    = alloc(64 * 4);
    const size_t o_cnt    = alloc(((size_t)3 * N_NODES + 1) * 4);
    const size_t o_cursor = alloc((size_t)3 * N_NODES * 4);
    const size_t o_col    = alloc((size_t)N_EDGES * 4);
    const int    nb_scan  = (3 * N_NODES + 1023) / 1024;
    const size_t o_part   = alloc((size_t)nb_scan * 4);
    const size_t o_pooled = alloc((size_t)NGRAPH * DIM * 4);
    const size_t o_gcnt   = alloc((size_t)NGRAPH * 4);

    if (ws_size < o) {
        fprintf(stderr, "GGNN kernel: workspace too small: need %zu, have %zu\n", o, ws_size);
        return;
    }

    int*   flag   = (int*)(ws + o_flag);
    u16*   xbf    = (u16*)(ws + o_xbf);
    u16*   A0     = (u16*)(ws + o_A0);
    u16*   A1     = (u16*)(ws + o_A1);
    u16*   A2     = (u16*)(ws + o_A2);
    u16*   B0     = (u16*)(ws + o_B0);
    u16*   B1     = (u16*)(ws + o_B1);
    float* Wt     = (float*)(ws + o_Wt);
    u16*   Wf_hi  = (u16*)(ws + o_Wf_hi);
    u16*   Wf_lo  = (u16*)(ws + o_Wf_lo);
    u16*   whh_hi = (u16*)(ws + o_whh_hi);
    u16*   whh_lo = (u16*)(ws + o_whh_lo);
    float* bihf   = (float*)(ws + o_bih);
    float* bhhf   = (float*)(ws + o_bhh);
    float* fc1wf  = (float*)(ws + o_fc1w);
    float* fc1bf  = (float*)(ws + o_fc1b);
    float* fc2wf  = (float*)(ws + o_fc2w);
    float* fc2bf  = (float*)(ws + o_fc2b);
    float* fclwf  = (float*)(ws + o_fclw);
    float* fclbf  = (float*)(ws + o_fclb);
    float* ptf    = (float*)(ws + o_ptf);
    int*   cnt    = (int*)(ws + o_cnt);
    int*   rp     = cnt;
    int*   cursor = (int*)(ws + o_cursor);
    int*   col    = (int*)(ws + o_col);
    int*   part   = (int*)(ws + o_part);
    float* pooled = (float*)(ws + o_pooled);
    int*   gcnt   = (int*)(ws + o_gcnt);

    hipMemsetAsync(cnt, 0, (size_t)3 * N_NODES * 4, stream);
    hipMemsetAsync(pooled, 0, (o_gcnt - o_pooled) + (size_t)NGRAPH * 4, stream);

    k_detect<<<1, 256, 0, stream>>>((const u16*)x_in, flag);

    // mega-prep (to_bf | transW | prep_G | convsmall in one launch), then fuse
    k_prep<<<PREP_BLOCKS, 256, 0, stream>>>(
        x_in, xbf, W_in, Wt, whh_in, whh_hi, whh_lo,
        bih_in, bhh_in, fc1w_in, fc1b_in, fc2w_in, fc2b_in, fclw_in, fclb_in, pt_in,
        bihf, bhhf, fc1wf, fc1bf, fc2wf, fc2bf, fclwf, fclbf, ptf, flag);
    k_fuse<<<(NSETS * NLAYERS * 384 * DIM) / 256, 256, 0, stream>>>(Wt, wih_in, Wf_hi, Wf_lo, flag);

    // CSR build
    k_deg<<<(N_EDGES + 255) / 256, 256, 0, stream>>>(ei, attr, cnt);
    k_scan1<<<nb_scan, 1024, 0, stream>>>(cnt, rp, part, 3 * N_NODES);
    k_scan2<<<1, 1024, 0, stream>>>(part, nb_scan);
    k_scan3<<<nb_scan, 1024, 0, stream>>>(rp, cursor, part, 3 * N_NODES);
    k_fill<<<(N_EDGES + 255) / 256, 256, 0, stream>>>(ei, attr, cursor, col);

    // GGC passes (split gather + persistent weight-resident gemm)
    for (int pass = 0; pass < NPASS; ++pass) {
        k_gather<<<3 * GT, 256, 0, stream>>>(xbf, xbf, xbf, A0, A1, A2, rp, col);
        k_gemm<<<3 * PB, 512, 0, stream>>>(A0, A1, A2, xbf, xbf, xbf, A0, A1, A2,
                                           Wf_hi, Wf_lo, whh_hi, whh_lo, bihf, bhhf, 0);
        k_gather<<<3 * GT, 256, 0, stream>>>(A0, A1, A2, B0, B1, xbf, rp, col);
        k_gemm<<<3 * PB, 512, 0, stream>>>(B0, B1, xbf, A0, A1, A2, A0, A1, A2,
                                           Wf_hi, Wf_lo, whh_hi, whh_lo, bihf, bhhf, 1);
        if (pass + 1 < NPASS)   // final-pass avg3 is fused into k_pool3
            k_avg3<<<(N_NODES * DIM / 8) / 256, 256, 0, stream>>>(A0, A1, A2, xbf);
    }

    // pooling (fused final avg3) + head
    k_pool3<<<MT, 256, 0, stream>>>(A0, A1, A2, batch, pooled, gcnt);
    k_head<<<NGRAPH, 128, 0, stream>>>(pooled, gcnt, ptf, fc1wf, fc1bf, fc2wf, fc2bf,
                                       fclwf, fclbf, d_out, flag);
}